// Round 6
// baseline (169.928 us; speedup 1.0000x reference)
//
#include <hip/hip_runtime.h>

// Problem constants: x [8,128,96,96] fp32, W [384,128] fp32, out [8,128,96,96] fp32.
#define NB     8
#define CIN    128
#define HEADS  4
#define DHEAD  32
#define HDIM   96
#define WDIM   96
#define HW     9216

// Fused-kernel tile geometry. One block = one (b, 8x8 spatial tile), 4 waves.
#define TH     8                 // interior rows per block
#define TW     8                 // interior cols per block
#define HR     (TH + 2)          // halo rows = 10
#define HC     (TW + 2)          // halo cols = 10
#define HP     (HR * HC)         // halo positions = 100
#define NT     7                 // position tiles of 16 (112 >= 100, pad OOB)
#define NPOS   (NT * 16)         // 112
#define NPOSP  (NPOS + 1)        // padded plane stride (uint4/float4 units)
#define QP     (TH * TW)         // 64 interior positions

// gfx950 builtins (cvt_pkrtz / fdot2 / mfma_*_f16) use __fp16 vectors.
typedef __fp16 f16x2 __attribute__((ext_vector_type(2)));
typedef __fp16 f16x8 __attribute__((ext_vector_type(8)));
typedef float  f32x4 __attribute__((ext_vector_type(4)));

__device__ __forceinline__ unsigned pkh2(float a, float b) {
  f16x2 h = __builtin_amdgcn_cvt_pkrtz(a, b);    // v_cvt_pkrtz_f16_f32, 1 instr
  return *(unsigned*)&h;
}
__device__ __forceinline__ float dot2(unsigned a, unsigned b, float c) {
#if __has_builtin(__builtin_amdgcn_fdot2)
  return __builtin_amdgcn_fdot2(*(f16x2*)&a, *(f16x2*)&b, c, false);  // v_dot2_f32_f16
#else
  f16x2 ha = *(f16x2*)&a, hb = *(f16x2*)&b;
  c = fmaf((float)ha[0], (float)hb[0], c);
  return fmaf((float)ha[1], (float)hb[1], c);
#endif
}

// ---------------------------------------------------------------------------
// Prep: pack W [384][128] fp32 into A-fragment-ordered f16 global buffer,
// PER-HEAD-CONTIGUOUS: ot' = g*6 + s*2 + ph (24 KB hot window per head-GEMM).
// Frag: lane l holds A[o=(s*8+g*2+ph)*16+(l&15)][c=kb*32+(l>>4)*8+j], j=0..7.
// ---------------------------------------------------------------------------
__global__ __launch_bounds__(256) void wpack_kernel(const float* __restrict__ W,
                                                    uint4* __restrict__ Wf) {
  const int u = blockIdx.x * 256 + threadIdx.x;   // 0..6143 = 24 ot' * 4 kb * 64 lanes
  const int lane = u & 63, kb = (u >> 6) & 3, otp = u >> 8;
  const int g = otp / 6, r = otp % 6, s = r >> 1, ph = r & 1;
  const int o = (s * 8 + g * 2 + ph) * 16 + (lane & 15);
  const int c0 = kb * 32 + (lane >> 4) * 8;
  const float4* w = (const float4*)(W + (size_t)o * CIN + c0);
  float4 w0 = w[0], w1 = w[1];
  uint4 rr;
  rr.x = pkh2(w0.x, w0.y); rr.y = pkh2(w0.z, w0.w);
  rr.z = pkh2(w1.x, w1.y); rr.w = pkh2(w1.z, w1.w);
  Wf[u] = rr;
}

// ---------------------------------------------------------------------------
// Fused kernel: block = (b, 8x8 tile), 256 threads = 4 waves.
//  Phase A: x halo (10x10, OOB -> 0) -> f16 MFMA B-frags in registers.
//           Waves 0-2 own pos-tiles {2wv, 2wv+1}; wave 3 owns tile 6.
//  Per head g: GEMM 6 o-tiles x (1|2) pos-tiles x 4 kb mfma_f32_16x16x32_f16;
//           Q,K f16 to LDS; V fp32 to LDS. Barrier. Attention:
//           thread = (pos 0..63, d-quarter 0..3); logits full-d via
//           v_dot2_f32_f16; PV 8 d/thread via v_fmac_f32 on fp32 V.
// OOB halo positions have zero x-frags -> K=V=0 -> logit exactly 0, zero V
// contribution == reference zero-pad semantics, branch-free.
// LDS: Q 4KB + K 7.2KB + V 14.5KB = 25.2KB -> 6 blocks/CU, 24 waves/CU.
// Grid 12x12x8 = 1152 blocks -> 4.5 blocks/CU of work, ~all co-resident.
// ---------------------------------------------------------------------------
__global__ __launch_bounds__(256, 6) void fused_kernel(const float* __restrict__ x,
                                                       const uint4* __restrict__ Wf,
                                                       float* __restrict__ out) {
  __shared__ uint4 qs[4 * QP];      //  4 KB   f16, interior positions only
  __shared__ uint4 ks[4 * NPOSP];   //  7.2 KB f16, halo
  __shared__ f32x4 vs[8 * NPOSP];   // 14.5 KB fp32, halo

  const int b  = blockIdx.z;
  const int h0 = blockIdx.y * TH;
  const int w0 = blockIdx.x * TW;
  const int t  = threadIdx.x;
  const int wv = t >> 6, lane = t & 63;
  const int colp = lane & 15, quad = lane >> 4;
  const int ntile = (wv == 3) ? 1 : 2;            // pos-tiles owned by this wave

  // ---- Phase A: x halo -> f16 B-fragments in registers ----
  uint4 frags[2][4];
  {
    const size_t xbase = (size_t)b * CIN * HW;
#pragma unroll
    for (int i = 0; i < 2; ++i) {
      if (i < ntile) {
        const int hp = (wv * 2 + i) * 16 + colp;
        const int hr = hp / HC, hc = hp - hr * HC;
        const int hh = h0 - 1 + hr, ww = w0 - 1 + hc;
        const bool ok = (hp < HP) & (hh >= 0) & (hh < HDIM) & (ww >= 0) & (ww < WDIM);
#pragma unroll
        for (int kb = 0; kb < 4; ++kb) {
          const int c0 = kb * 32 + quad * 8;
          float f[8] = {0.f, 0.f, 0.f, 0.f, 0.f, 0.f, 0.f, 0.f};
          if (ok) {
            const size_t pb = xbase + (size_t)(hh * WDIM + ww);
#pragma unroll
            for (int j = 0; j < 8; ++j) f[j] = x[pb + (size_t)(c0 + j) * HW];
          }
          uint4 r;
          r.x = pkh2(f[0], f[1]); r.y = pkh2(f[2], f[3]);
          r.z = pkh2(f[4], f[5]); r.w = pkh2(f[6], f[7]);
          frags[i][kb] = r;
        }
      }
    }
  }

  // attn identity: thread = (pos, d-quarter)
  const int pos = t & 63, dq = t >> 6;
  const int y = pos >> 3, xx = pos & 7;
  const int pbase = (y + 1) * HC + (xx + 1);

#pragma unroll 1
  for (int g = 0; g < 4; ++g) {
    if (g) __syncthreads();                      // prev head's attn reads done

    // ---- GEMM for head g: s=0:Q, 1:K, 2:V; ph = lo/hi 16 of 32 d ----
#pragma unroll
    for (int s = 0; s < 3; ++s) {
#pragma unroll
      for (int ph = 0; ph < 2; ++ph) {
        const int otp = g * 6 + s * 2 + ph;      // per-head-contiguous Wf
        f16x8 af[4];
#pragma unroll
        for (int kb = 0; kb < 4; ++kb) {
          uint4 tmp = Wf[(otp * 4 + kb) * 64 + lane];   // L1/L2-hot, coalesced
          af[kb] = *(f16x8*)&tmp;
        }
        const int d0 = ph * 16 + quad * 4;       // 4 consecutive d (regs 0..3)
#pragma unroll
        for (int i = 0; i < 2; ++i) {
          if (i < ntile) {
            f32x4 acc = {0.f, 0.f, 0.f, 0.f};
#pragma unroll
            for (int kb = 0; kb < 4; ++kb)
              acc = __builtin_amdgcn_mfma_f32_16x16x32_f16(
                  af[kb], *(f16x8*)&frags[i][kb], acc, 0, 0, 0);
            const int pw = (wv * 2 + i) * 16 + colp;
            if (s == 2) {
              vs[(d0 >> 2) * NPOSP + pw] = acc;  // fp32 V, ds_write_b128
            } else {
              uint2 st;
              st.x = pkh2(acc[0], acc[1]);
              st.y = pkh2(acc[2], acc[3]);
              if (s == 0) {
                const int hr = pw / HC, hc = pw - hr * HC;
                if (((unsigned)(hr - 1) < TH) & ((unsigned)(hc - 1) < TW)) {
                  const int idx = (hr - 1) * TW + (hc - 1);
                  *(uint2*)((unsigned short*)(qs + (d0 >> 3) * QP + idx)
                            + ((d0 >> 2) & 1) * 4) = st;
                }
              } else {
                *(uint2*)((unsigned short*)(ks + (d0 >> 3) * NPOSP + pw)
                          + ((d0 >> 2) & 1) * 4) = st;
              }
            }
          }
        }
      }
    }
    __syncthreads();

    // ---- attention for head g ----
    unsigned qp[16];                              // 16 x half2 = full 32-d Q
#pragma unroll
    for (int c = 0; c < 4; ++c) {
      uint4 u = qs[c * QP + pos];
      qp[c * 4 + 0] = u.x; qp[c * 4 + 1] = u.y;
      qp[c * 4 + 2] = u.z; qp[c * 4 + 3] = u.w;
    }

    float att[9];
#pragma unroll
    for (int nn = 0; nn < 9; ++nn) {
      const int pn = pbase + (nn / 3 - 1) * HC + (nn % 3 - 1);
      float dot = 0.0f;
#pragma unroll
      for (int c = 0; c < 4; ++c) {
        uint4 ku = ks[c * NPOSP + pn];
        dot = dot2(qp[c * 4 + 0], ku.x, dot);
        dot = dot2(qp[c * 4 + 1], ku.y, dot);
        dot = dot2(qp[c * 4 + 2], ku.z, dot);
        dot = dot2(qp[c * 4 + 3], ku.w, dot);
      }
      att[nn] = dot * 0.17677669529663687f;   // 1/sqrt(32)
    }

    float m = att[0];
#pragma unroll
    for (int nn = 1; nn < 9; ++nn) m = fmaxf(m, att[nn]);
    float ssum = 0.0f;
#pragma unroll
    for (int nn = 0; nn < 9; ++nn) { att[nn] = __expf(att[nn] - m); ssum += att[nn]; }
    const float inv = 1.0f / ssum;

    f32x4 acc4[2];
#pragma unroll
    for (int j = 0; j < 2; ++j) acc4[j] = (f32x4){0.f, 0.f, 0.f, 0.f};
#pragma unroll
    for (int nn = 0; nn < 9; ++nn) {
      const float wn = att[nn] * inv;
      const int pn = pbase + (nn / 3 - 1) * HC + (nn % 3 - 1);
#pragma unroll
      for (int j = 0; j < 2; ++j) {
        f32x4 vv = vs[(dq * 2 + j) * NPOSP + pn];
        acc4[j] += wn * vv;                      // v_fmac_f32
      }
    }

    // out [b][C=128][96][96]; channel = g*32 + dq*8 + j*4 + e
    float* ob = out + ((size_t)b * CIN + (size_t)g * DHEAD + (size_t)dq * 8) * HW
              + (size_t)(h0 + y) * WDIM + (w0 + xx);
#pragma unroll
    for (int j = 0; j < 2; ++j)
#pragma unroll
      for (int e = 0; e < 4; ++e)
        ob[(size_t)(j * 4 + e) * HW] = acc4[j][e];
  }
}

extern "C" void kernel_launch(void* const* d_in, const int* in_sizes, int n_in,
                              void* d_out, int out_size, void* d_ws, size_t ws_size,
                              hipStream_t stream) {
  (void)in_sizes; (void)n_in; (void)out_size; (void)ws_size;
  const float* x = (const float*)d_in[0];   // [8,128,96,96]
  const float* W = (const float*)d_in[1];   // [384,128]
  float* out = (float*)d_out;

  uint4* Wf = (uint4*)d_ws;                 // 96 KB packed weights

  wpack_kernel<<<24, 256, 0, stream>>>(W, Wf);
  fused_kernel<<<dim3(WDIM / TW, HDIM / TH, NB), 256, 0, stream>>>(x, Wf, out);
}

// Round 7
// 119.805 us; speedup vs baseline: 1.4184x; 1.4184x over previous
//
#include <hip/hip_runtime.h>

// Problem constants: x [8,128,96,96] fp32, W [384,128] fp32, out [8,128,96,96] fp32.
#define NB     8
#define CIN    128
#define HEADS  4
#define DHEAD  32
#define HDIM   96
#define WDIM   96
#define HW     9216

// Fused-kernel tile geometry. One block = (b, head-pair, 8x16 tile), 4 waves.
#define TH     8                 // interior rows per block
#define TW     16                // interior cols per block
#define HR     (TH + 2)          // halo rows = 10
#define HC     (TW + 2)          // halo cols = 18
#define HP     (HR * HC)         // halo positions = 180
#define NT     12                // position tiles of 16 (192 >= 180, pad OOB)
#define NPOS   (NT * 16)         // 192
#define NPOSP  (NPOS + 1)        // padded plane stride (uint4 units)
#define QP     (TH * TW)         // 128 interior positions

// gfx950 builtins (cvt_pkrtz / fdot2 / mfma_*_f16) use __fp16 vectors.
typedef __fp16 f16x2 __attribute__((ext_vector_type(2)));
typedef __fp16 f16x8 __attribute__((ext_vector_type(8)));
typedef float  f32x4 __attribute__((ext_vector_type(4)));

__device__ __forceinline__ unsigned pkh2(float a, float b) {
  f16x2 h = __builtin_amdgcn_cvt_pkrtz(a, b);    // v_cvt_pkrtz_f16_f32
  return *(unsigned*)&h;
}
__device__ __forceinline__ float dot2(unsigned a, unsigned b, float c) {
#if __has_builtin(__builtin_amdgcn_fdot2)
  return __builtin_amdgcn_fdot2(*(f16x2*)&a, *(f16x2*)&b, c, false);  // v_dot2_f32_f16
#else
  f16x2 ha = *(f16x2*)&a, hb = *(f16x2*)&b;
  c = fmaf((float)ha[0], (float)hb[0], c);
  return fmaf((float)ha[1], (float)hb[1], c);
#endif
}

// ---------------------------------------------------------------------------
// xpack: transpose x [b][c][p] fp32 -> xT [b][p][c] f16 (256 B per position).
// Makes every downstream halo read position-contiguous & fully line-utilized.
// ---------------------------------------------------------------------------
__global__ __launch_bounds__(256) void xpack_kernel(const float* __restrict__ x,
                                                    uint4* __restrict__ xT) {
  __shared__ unsigned l[64 * 67];                 // [pos][64 c-pair uints], pad 3
  const int b  = blockIdx.y;
  const int p0 = blockIdx.x * 64;
  const int t  = threadIdx.x;
  const int p  = t & 63, cg = t >> 6;             // cg: 32-channel group
  const float* xb = x + (size_t)b * CIN * HW + p0 + p;
#pragma unroll
  for (int i = 0; i < 16; ++i) {
    const int c = cg * 32 + 2 * i;
    float f0 = xb[(size_t)c * HW];                // coalesced along p
    float f1 = xb[(size_t)(c + 1) * HW];
    l[p * 67 + cg * 16 + i] = pkh2(f0, f1);
  }
  __syncthreads();
  uint4* dst = xT + ((size_t)b * HW + p0) * 16;   // 16 uint4 per position
#pragma unroll
  for (int k = 0; k < 4; ++k) {
    const int u = k * 256 + t;                    // 1024 uint4 per block
    const int pos = u >> 4, ch = u & 15;
    uint4 d;
    d.x = l[pos * 67 + ch * 4 + 0];
    d.y = l[pos * 67 + ch * 4 + 1];
    d.z = l[pos * 67 + ch * 4 + 2];
    d.w = l[pos * 67 + ch * 4 + 3];
    dst[u] = d;                                   // fully coalesced 1KB/instr
  }
}

// ---------------------------------------------------------------------------
// wpack: W [384][128] fp32 -> A-fragment-ordered f16, PER-HEAD-CONTIGUOUS:
// otp = g*6 + s*2 + ph (24 KB hot window per head GEMM).
// Frag: lane l holds A[o=(s*8+g*2+ph)*16+(l&15)][c=kb*32+(l>>4)*8+j], j=0..7.
// ---------------------------------------------------------------------------
__global__ __launch_bounds__(256) void wpack_kernel(const float* __restrict__ W,
                                                    uint4* __restrict__ Wf) {
  const int u = blockIdx.x * 256 + threadIdx.x;   // 24 otp * 4 kb * 64 lanes
  const int lane = u & 63, kb = (u >> 6) & 3, otp = u >> 8;
  const int g = otp / 6, r = otp % 6, s = r >> 1, ph = r & 1;
  const int o = (s * 8 + g * 2 + ph) * 16 + (lane & 15);
  const int c0 = kb * 32 + (lane >> 4) * 8;
  const float4* w = (const float4*)(W + (size_t)o * CIN + c0);
  float4 w0 = w[0], w1 = w[1];
  uint4 rr;
  rr.x = pkh2(w0.x, w0.y); rr.y = pkh2(w0.z, w0.w);
  rr.z = pkh2(w1.x, w1.y); rr.w = pkh2(w1.z, w1.w);
  Wf[u] = rr;
}

// ---------------------------------------------------------------------------
// Fused kernel: block = (b, head-pair, 8x16 tile), 256 threads = 4 waves.
//  Phase A: xT halo (10x18, OOB -> 0) -> f16 B-frags: ONE uint4 load per
//           (pos-tile, kb) -- positions 256B-contiguous, full line use.
//  Per head g (2 per block): GEMM 6 o-tiles x 3 pos-tiles x 4 kb
//           mfma_f32_16x16x32_f16; Q (interior) / K / V all f16 to LDS.
//           Barrier. Attention: thread = (pos 0..127, d-half); logits full-d
//           via v_dot2_f32_f16; PV 16 d/thread via mixed f16xf32 FMA.
// OOB halo positions have zero x-frags -> K=V=0 -> logit exactly 0, zero V
// contribution == reference zero-pad semantics, branch-free.
// LDS: Q 8KB + K 12.1KB + V 12.1KB = 32.7KB -> 4 blocks/CU, 16 waves/CU.
// Grid 6x12x16 = 1152 blocks -> 4.5 blocks/CU of work.
// ---------------------------------------------------------------------------
__global__ __launch_bounds__(256, 4) void fused_kernel(const uint4* __restrict__ xT,
                                                       const uint4* __restrict__ Wf,
                                                       float* __restrict__ out) {
  __shared__ uint4 qs[4 * QP];      //  8 KB   f16, interior positions only
  __shared__ uint4 ks[4 * NPOSP];   // 12.1 KB f16, halo
  __shared__ uint4 vs[4 * NPOSP];   // 12.1 KB f16, halo

  const int z  = blockIdx.z;
  const int b  = z >> 1, hpair = z & 1;           // head pair {0,1} or {2,3}
  const int h0 = blockIdx.y * TH;
  const int w0 = blockIdx.x * TW;
  const int t  = threadIdx.x;
  const int wv = t >> 6, lane = t & 63;
  const int colp = lane & 15, quad = lane >> 4;

  // ---- Phase A: xT halo -> f16 B-fragments (wave owns pos-tiles wv*3..+2) ----
  uint4 frags[3][4];
  {
    const size_t xb16 = (size_t)b * HW * 16;      // uint4 units
#pragma unroll
    for (int i = 0; i < 3; ++i) {
      const int hp = (wv * 3 + i) * 16 + colp;
      const int hr = hp / HC, hc = hp - hr * HC;
      const int hh = h0 - 1 + hr, ww = w0 - 1 + hc;
      const bool ok = (hp < HP) & (hh >= 0) & (hh < HDIM) & (ww >= 0) & (ww < WDIM);
#pragma unroll
      for (int kb = 0; kb < 4; ++kb) {
        uint4 r = {0u, 0u, 0u, 0u};
        if (ok)
          r = xT[xb16 + (size_t)(hh * WDIM + ww) * 16 + kb * 4 + quad];
        frags[i][kb] = r;
      }
    }
  }

  // attn identity: thread = (pos, d-half)
  const int pos = t & 127, dh = t >> 7;
  const int y = pos >> 4, xx = pos & 15;
  const int pbase = (y + 1) * HC + (xx + 1);

#pragma unroll 1
  for (int gi = 0; gi < 2; ++gi) {
    const int g = hpair * 2 + gi;
    if (gi) __syncthreads();                      // prev head's attn reads done

    // ---- GEMM for head g: s=0:Q, 1:K, 2:V; ph = lo/hi 16 of 32 d ----
#pragma unroll
    for (int s = 0; s < 3; ++s) {
#pragma unroll
      for (int ph = 0; ph < 2; ++ph) {
        const int otp = g * 6 + s * 2 + ph;       // per-head-contiguous Wf
        f16x8 af[4];
#pragma unroll
        for (int kb = 0; kb < 4; ++kb) {
          uint4 tmp = Wf[(otp * 4 + kb) * 64 + lane];   // L2-hot, coalesced
          af[kb] = *(f16x8*)&tmp;
        }
        const int d0 = ph * 16 + quad * 4;        // 4 consecutive d (regs 0..3)
#pragma unroll
        for (int i = 0; i < 3; ++i) {
          f32x4 acc = {0.f, 0.f, 0.f, 0.f};
#pragma unroll
          for (int kb = 0; kb < 4; ++kb)
            acc = __builtin_amdgcn_mfma_f32_16x16x32_f16(
                af[kb], *(f16x8*)&frags[i][kb], acc, 0, 0, 0);
          const int pw = (wv * 3 + i) * 16 + colp;
          uint2 st;
          st.x = pkh2(acc[0], acc[1]);
          st.y = pkh2(acc[2], acc[3]);
          if (s == 0) {
            const int hr = pw / HC, hc = pw - hr * HC;
            if (((unsigned)(hr - 1) < TH) & ((unsigned)(hc - 1) < TW)) {
              const int idx = (hr - 1) * TW + (hc - 1);
              *(uint2*)((unsigned short*)(qs + (d0 >> 3) * QP + idx)
                        + ((d0 >> 2) & 1) * 4) = st;
            }
          } else {
            uint4* dst = (s == 1) ? ks : vs;
            *(uint2*)((unsigned short*)(dst + (d0 >> 3) * NPOSP + pw)
                      + ((d0 >> 2) & 1) * 4) = st;
          }
        }
      }
    }
    __syncthreads();

    // ---- attention for head g ----
    unsigned qp[16];                              // 16 x half2 = full 32-d Q
#pragma unroll
    for (int c = 0; c < 4; ++c) {
      uint4 u = qs[c * QP + pos];
      qp[c * 4 + 0] = u.x; qp[c * 4 + 1] = u.y;
      qp[c * 4 + 2] = u.z; qp[c * 4 + 3] = u.w;
    }

    float att[9];
#pragma unroll
    for (int nn = 0; nn < 9; ++nn) {
      const int pn = pbase + (nn / 3 - 1) * HC + (nn % 3 - 1);
      float dot = 0.0f;
#pragma unroll
      for (int c = 0; c < 4; ++c) {
        uint4 ku = ks[c * NPOSP + pn];
        dot = dot2(qp[c * 4 + 0], ku.x, dot);
        dot = dot2(qp[c * 4 + 1], ku.y, dot);
        dot = dot2(qp[c * 4 + 2], ku.z, dot);
        dot = dot2(qp[c * 4 + 3], ku.w, dot);
      }
      att[nn] = dot * 0.17677669529663687f;   // 1/sqrt(32)
    }

    float m = att[0];
#pragma unroll
    for (int nn = 1; nn < 9; ++nn) m = fmaxf(m, att[nn]);
    float ssum = 0.0f;
#pragma unroll
    for (int nn = 0; nn < 9; ++nn) { att[nn] = __expf(att[nn] - m); ssum += att[nn]; }
    const float inv = 1.0f / ssum;

    float acc[16];
#pragma unroll
    for (int i = 0; i < 16; ++i) acc[i] = 0.0f;
#pragma unroll
    for (int nn = 0; nn < 9; ++nn) {
      const float wn = att[nn] * inv;
      const int pn = pbase + (nn / 3 - 1) * HC + (nn % 3 - 1);
#pragma unroll
      for (int cc = 0; cc < 2; ++cc) {            // d-planes dh*2+cc
        uint4 vv = vs[(dh * 2 + cc) * NPOSP + pn];
        f16x2 h0 = *(f16x2*)&vv.x, h1 = *(f16x2*)&vv.y;
        f16x2 h2 = *(f16x2*)&vv.z, h3 = *(f16x2*)&vv.w;
        acc[cc * 8 + 0] = fmaf(wn, (float)h0[0], acc[cc * 8 + 0]);  // v_fma_mix
        acc[cc * 8 + 1] = fmaf(wn, (float)h0[1], acc[cc * 8 + 1]);
        acc[cc * 8 + 2] = fmaf(wn, (float)h1[0], acc[cc * 8 + 2]);
        acc[cc * 8 + 3] = fmaf(wn, (float)h1[1], acc[cc * 8 + 3]);
        acc[cc * 8 + 4] = fmaf(wn, (float)h2[0], acc[cc * 8 + 4]);
        acc[cc * 8 + 5] = fmaf(wn, (float)h2[1], acc[cc * 8 + 5]);
        acc[cc * 8 + 6] = fmaf(wn, (float)h3[0], acc[cc * 8 + 6]);
        acc[cc * 8 + 7] = fmaf(wn, (float)h3[1], acc[cc * 8 + 7]);
      }
    }

    // out [b][C=128][96][96]; channel = g*32 + dh*16 + i; lanes along w
    float* ob = out + ((size_t)b * CIN + (size_t)g * DHEAD + (size_t)dh * 16) * HW
              + (size_t)(h0 + y) * WDIM + (w0 + xx);
#pragma unroll
    for (int i = 0; i < 16; ++i) ob[(size_t)i * HW] = acc[i];
  }
}

extern "C" void kernel_launch(void* const* d_in, const int* in_sizes, int n_in,
                              void* d_out, int out_size, void* d_ws, size_t ws_size,
                              hipStream_t stream) {
  (void)in_sizes; (void)n_in; (void)out_size; (void)ws_size;
  const float* x = (const float*)d_in[0];   // [8,128,96,96]
  const float* W = (const float*)d_in[1];   // [384,128]
  float* out = (float*)d_out;

  uint4* xT = (uint4*)d_ws;                              // 18.87 MB channel-last f16
  uint4* Wf = (uint4*)((char*)d_ws + (size_t)NB * HW * 256);  // 96 KB packed weights

  xpack_kernel<<<dim3(HW / 64, NB), 256, 0, stream>>>(x, xT);
  wpack_kernel<<<24, 256, 0, stream>>>(W, Wf);
  fused_kernel<<<dim3(WDIM / TW, HDIM / TH, NB * 2), 256, 0, stream>>>(xT, Wf, out);
}

// Round 8
// 116.744 us; speedup vs baseline: 1.4556x; 1.0262x over previous
//
#include <hip/hip_runtime.h>

// Problem constants: x [8,128,96,96] fp32, W [384,128] fp32, out [8,128,96,96] fp32.
#define NB     8
#define CIN    128
#define HEADS  4
#define DHEAD  32
#define HDIM   96
#define WDIM   96
#define HW     9216

// Fused-kernel tile geometry. One block = (b, head, 8x16 tile), 4 waves.
#define TH     8                 // interior rows per block
#define TW     16                // interior cols per block
#define HR     (TH + 2)          // halo rows = 10
#define HC     (TW + 2)          // halo cols = 18
#define HP     (HR * HC)         // halo positions = 180
#define NT     12                // position tiles of 16 (192 >= 180, pad OOB)
#define NPOS   (NT * 16)         // 192 (no plane pad: no LDS instr crosses planes)
#define QP     (TH * TW)         // 128 interior positions

// gfx950 builtins (cvt_pkrtz / fdot2 / mfma_*_f16) use __fp16 vectors.
typedef __fp16 f16x2 __attribute__((ext_vector_type(2)));
typedef __fp16 f16x8 __attribute__((ext_vector_type(8)));
typedef float  f32x4 __attribute__((ext_vector_type(4)));

__device__ __forceinline__ unsigned pkh2(float a, float b) {
  f16x2 h = __builtin_amdgcn_cvt_pkrtz(a, b);    // v_cvt_pkrtz_f16_f32
  return *(unsigned*)&h;
}
__device__ __forceinline__ float dot2(unsigned a, unsigned b, float c) {
#if __has_builtin(__builtin_amdgcn_fdot2)
  return __builtin_amdgcn_fdot2(*(f16x2*)&a, *(f16x2*)&b, c, false);  // v_dot2_f32_f16
#else
  f16x2 ha = *(f16x2*)&a, hb = *(f16x2*)&b;
  c = fmaf((float)ha[0], (float)hb[0], c);
  return fmaf((float)ha[1], (float)hb[1], c);
#endif
}

#define XBLKS (NB * (HW / 64))   // 1152 xpack blocks

// ---------------------------------------------------------------------------
// prep: (a) xpack: x [b][c][p] fp32 -> xT [b][p][c] f16 (256 B/position) via
// LDS transpose, fully coalesced both sides; (b) wpack: W -> A-frag-ordered
// f16, PER-HEAD-CONTIGUOUS otp = g*6 + s*2 + ph (24 KB hot window per head).
// ---------------------------------------------------------------------------
__global__ __launch_bounds__(256) void prep_kernel(const float* __restrict__ x,
                                                   const float* __restrict__ W,
                                                   uint4* __restrict__ xT,
                                                   uint4* __restrict__ Wf) {
  __shared__ unsigned l[64 * 67];                 // [pos][64 c-pair uints], pad 3
  const int bid = blockIdx.x;
  const int t   = threadIdx.x;
  if (bid < XBLKS) {
    const int b  = bid / (HW / 64);
    const int p0 = (bid % (HW / 64)) * 64;
    const int p  = t & 63, cg = t >> 6;           // cg: 32-channel group
    const float* xb = x + (size_t)b * CIN * HW + p0 + p;
#pragma unroll
    for (int i = 0; i < 16; ++i) {
      const int c = cg * 32 + 2 * i;
      float f0 = xb[(size_t)c * HW];              // coalesced along p
      float f1 = xb[(size_t)(c + 1) * HW];
      l[p * 67 + cg * 16 + i] = pkh2(f0, f1);
    }
    __syncthreads();
    uint4* dst = xT + ((size_t)b * HW + p0) * 16; // 16 uint4 per position
#pragma unroll
    for (int k = 0; k < 4; ++k) {
      const int u = k * 256 + t;                  // 1024 uint4 per block
      const int pos = u >> 4, ch = u & 15;
      uint4 d;
      d.x = l[pos * 67 + ch * 4 + 0];
      d.y = l[pos * 67 + ch * 4 + 1];
      d.z = l[pos * 67 + ch * 4 + 2];
      d.w = l[pos * 67 + ch * 4 + 3];
      dst[u] = d;                                 // fully coalesced 1KB/instr
    }
  } else {
    const int u = (bid - XBLKS) * 256 + t;        // 24 otp * 4 kb * 64 lanes
    const int lane = u & 63, kb = (u >> 6) & 3, otp = u >> 8;
    const int g = otp / 6, r = otp % 6, s = r >> 1, ph = r & 1;
    const int o = (s * 8 + g * 2 + ph) * 16 + (lane & 15);
    const int c0 = kb * 32 + (lane >> 4) * 8;
    const float4* w = (const float4*)(W + (size_t)o * CIN + c0);
    float4 w0 = w[0], w1 = w[1];
    uint4 rr;
    rr.x = pkh2(w0.x, w0.y); rr.y = pkh2(w0.z, w0.w);
    rr.z = pkh2(w1.x, w1.y); rr.w = pkh2(w1.z, w1.w);
    Wf[u] = rr;
  }
}

// ---------------------------------------------------------------------------
// Fused kernel: block = (b, head g, 8x16 tile), 256 threads = 4 waves.
//  Phase A: xT halo (10x18, OOB -> 0) -> f16 B-frags: one uint4 load per
//           (pos-tile, kb) -- positions 256B-contiguous, full line use.
//  GEMM (head g): 6 o-tiles x 3 pos-tiles x 4 kb mfma_f32_16x16x32_f16;
//           Q (interior) / K / V all f16 to LDS. ONE barrier. Attention:
//           thread = (pos 0..127, d-half); logits full-d via v_dot2_f32_f16;
//           PV 16 d/thread via mixed f16xf32 FMA.
// OOB halo positions have zero x-frags -> K=V=0 -> logit exactly 0, zero V
// contribution == reference zero-pad semantics, branch-free.
// LDS: Q 8KB + K 12KB + V 12KB = 32KB exactly -> 5 blocks/CU, 20 waves/CU.
// Grid 6x12x32 = 2304 blocks -> 9 blocks/CU of work; heads of one tile are
// 72 block-ids apart (0 mod 8) -> same XCD -> xT halo L2-hot across heads.
// ---------------------------------------------------------------------------
__global__ __launch_bounds__(256, 5) void fused_kernel(const uint4* __restrict__ xT,
                                                       const uint4* __restrict__ Wf,
                                                       float* __restrict__ out) {
  __shared__ uint4 qs[4 * QP];     //  8 KB f16, interior positions only
  __shared__ uint4 ks[4 * NPOS];   // 12 KB f16, halo
  __shared__ uint4 vs[4 * NPOS];   // 12 KB f16, halo

  const int z  = blockIdx.z;
  const int b  = z >> 2, g = z & 3;
  const int h0 = blockIdx.y * TH;
  const int w0 = blockIdx.x * TW;
  const int t  = threadIdx.x;
  const int wv = t >> 6, lane = t & 63;
  const int colp = lane & 15, quad = lane >> 4;

  // ---- Phase A: xT halo -> f16 B-fragments (wave owns pos-tiles wv*3..+2) ----
  uint4 frags[3][4];
  {
    const size_t xb16 = (size_t)b * HW * 16;      // uint4 units
#pragma unroll
    for (int i = 0; i < 3; ++i) {
      const int hp = (wv * 3 + i) * 16 + colp;
      const int hr = hp / HC, hc = hp - hr * HC;
      const int hh = h0 - 1 + hr, ww = w0 - 1 + hc;
      const bool ok = (hp < HP) & (hh >= 0) & (hh < HDIM) & (ww >= 0) & (ww < WDIM);
#pragma unroll
      for (int kb = 0; kb < 4; ++kb) {
        uint4 r = {0u, 0u, 0u, 0u};
        if (ok)
          r = xT[xb16 + (size_t)(hh * WDIM + ww) * 16 + kb * 4 + quad];
        frags[i][kb] = r;
      }
    }
  }

  // ---- GEMM for head g: s=0:Q, 1:K, 2:V; ph = lo/hi 16 of 32 d ----
#pragma unroll
  for (int s = 0; s < 3; ++s) {
#pragma unroll
    for (int ph = 0; ph < 2; ++ph) {
      const int otp = g * 6 + s * 2 + ph;         // per-head-contiguous Wf
      f16x8 af[4];
#pragma unroll
      for (int kb = 0; kb < 4; ++kb) {
        uint4 tmp = Wf[(otp * 4 + kb) * 64 + lane];   // L2-hot, coalesced
        af[kb] = *(f16x8*)&tmp;
      }
      const int d0 = ph * 16 + quad * 4;          // 4 consecutive d (regs 0..3)
#pragma unroll
      for (int i = 0; i < 3; ++i) {
        f32x4 acc = {0.f, 0.f, 0.f, 0.f};
#pragma unroll
        for (int kb = 0; kb < 4; ++kb)
          acc = __builtin_amdgcn_mfma_f32_16x16x32_f16(
              af[kb], *(f16x8*)&frags[i][kb], acc, 0, 0, 0);
        const int pw = (wv * 3 + i) * 16 + colp;
        uint2 st;
        st.x = pkh2(acc[0], acc[1]);
        st.y = pkh2(acc[2], acc[3]);
        if (s == 0) {
          const int hr = pw / HC, hc = pw - hr * HC;
          if (((unsigned)(hr - 1) < TH) & ((unsigned)(hc - 1) < TW)) {
            const int idx = (hr - 1) * TW + (hc - 1);
            *(uint2*)((unsigned short*)(qs + (d0 >> 3) * QP + idx)
                      + ((d0 >> 2) & 1) * 4) = st;
          }
        } else {
          uint4* dst = (s == 1) ? ks : vs;
          *(uint2*)((unsigned short*)(dst + (d0 >> 3) * NPOS + pw)
                    + ((d0 >> 2) & 1) * 4) = st;
        }
      }
    }
  }
  __syncthreads();

  // ---- attention: thread = (pos, d-half) ----
  const int pos = t & 127, dh = t >> 7;
  const int y = pos >> 4, xx = pos & 15;
  const int pbase = (y + 1) * HC + (xx + 1);

  unsigned qp[16];                                // 16 x half2 = full 32-d Q
#pragma unroll
  for (int c = 0; c < 4; ++c) {
    uint4 u = qs[c * QP + pos];
    qp[c * 4 + 0] = u.x; qp[c * 4 + 1] = u.y;
    qp[c * 4 + 2] = u.z; qp[c * 4 + 3] = u.w;
  }

  float att[9];
#pragma unroll
  for (int nn = 0; nn < 9; ++nn) {
    const int pn = pbase + (nn / 3 - 1) * HC + (nn % 3 - 1);
    float dot = 0.0f;
#pragma unroll
    for (int c = 0; c < 4; ++c) {
      uint4 ku = ks[c * NPOS + pn];
      dot = dot2(qp[c * 4 + 0], ku.x, dot);
      dot = dot2(qp[c * 4 + 1], ku.y, dot);
      dot = dot2(qp[c * 4 + 2], ku.z, dot);
      dot = dot2(qp[c * 4 + 3], ku.w, dot);
    }
    att[nn] = dot * 0.17677669529663687f;   // 1/sqrt(32)
  }

  float m = att[0];
#pragma unroll
  for (int nn = 1; nn < 9; ++nn) m = fmaxf(m, att[nn]);
  float ssum = 0.0f;
#pragma unroll
  for (int nn = 0; nn < 9; ++nn) { att[nn] = __expf(att[nn] - m); ssum += att[nn]; }
  const float inv = 1.0f / ssum;

  float acc[16];
#pragma unroll
  for (int i = 0; i < 16; ++i) acc[i] = 0.0f;
#pragma unroll
  for (int nn = 0; nn < 9; ++nn) {
    const float wn = att[nn] * inv;
    const int pn = pbase + (nn / 3 - 1) * HC + (nn % 3 - 1);
#pragma unroll
    for (int cc = 0; cc < 2; ++cc) {              // d-planes dh*2+cc
      uint4 vv = vs[(dh * 2 + cc) * NPOS + pn];
      f16x2 h0 = *(f16x2*)&vv.x, h1 = *(f16x2*)&vv.y;
      f16x2 h2 = *(f16x2*)&vv.z, h3 = *(f16x2*)&vv.w;
      acc[cc * 8 + 0] = fmaf(wn, (float)h0[0], acc[cc * 8 + 0]);  // v_fma_mix
      acc[cc * 8 + 1] = fmaf(wn, (float)h0[1], acc[cc * 8 + 1]);
      acc[cc * 8 + 2] = fmaf(wn, (float)h1[0], acc[cc * 8 + 2]);
      acc[cc * 8 + 3] = fmaf(wn, (float)h1[1], acc[cc * 8 + 3]);
      acc[cc * 8 + 4] = fmaf(wn, (float)h2[0], acc[cc * 8 + 4]);
      acc[cc * 8 + 5] = fmaf(wn, (float)h2[1], acc[cc * 8 + 5]);
      acc[cc * 8 + 6] = fmaf(wn, (float)h3[0], acc[cc * 8 + 6]);
      acc[cc * 8 + 7] = fmaf(wn, (float)h3[1], acc[cc * 8 + 7]);
    }
  }

  // out [b][C=128][96][96]; channel = g*32 + dh*16 + i; lanes along w
  float* ob = out + ((size_t)b * CIN + (size_t)g * DHEAD + (size_t)dh * 16) * HW
            + (size_t)(h0 + y) * WDIM + (w0 + xx);
#pragma unroll
  for (int i = 0; i < 16; ++i) ob[(size_t)i * HW] = acc[i];
}

extern "C" void kernel_launch(void* const* d_in, const int* in_sizes, int n_in,
                              void* d_out, int out_size, void* d_ws, size_t ws_size,
                              hipStream_t stream) {
  (void)in_sizes; (void)n_in; (void)out_size; (void)ws_size;
  const float* x = (const float*)d_in[0];   // [8,128,96,96]
  const float* W = (const float*)d_in[1];   // [384,128]
  float* out = (float*)d_out;

  uint4* xT = (uint4*)d_ws;                              // 18.87 MB channel-last f16
  uint4* Wf = (uint4*)((char*)d_ws + (size_t)NB * HW * 256);  // 96 KB packed weights

  prep_kernel<<<XBLKS + 24, 256, 0, stream>>>(x, W, xT, Wf);
  fused_kernel<<<dim3(WDIM / TW, HDIM / TH, NB * HEADS), 256, 0, stream>>>(xT, Wf, out);
}

// Round 9
// 116.600 us; speedup vs baseline: 1.4574x; 1.0012x over previous
//
#include <hip/hip_runtime.h>

// Problem constants: x [8,128,96,96] fp32, W [384,128] fp32, out [8,128,96,96] fp32.
#define NB     8
#define CIN    128
#define HEADS  4
#define DHEAD  32
#define HDIM   96
#define WDIM   96
#define HW     9216

// Fused-kernel tile geometry. One block = (b, head, 8x16 tile), 4 waves.
#define TH     8                 // interior rows per block
#define TW     16                // interior cols per block
#define HR     (TH + 2)          // halo rows = 10
#define HC     (TW + 2)          // halo cols = 18
#define HP     (HR * HC)         // halo positions = 180
#define NT     12                // position tiles of 16 (192 >= 180, pad OOB)
#define NPOS   (NT * 16)         // 192 (no plane pad: no LDS instr crosses planes)
#define QP     (TH * TW)         // 128 interior positions

// gfx950 builtins (cvt_pkrtz / fdot2 / mfma_*_f16) use __fp16 vectors.
typedef __fp16 f16x2 __attribute__((ext_vector_type(2)));
typedef __fp16 f16x8 __attribute__((ext_vector_type(8)));
typedef float  f32x4 __attribute__((ext_vector_type(4)));

__device__ __forceinline__ unsigned pkh2(float a, float b) {
  f16x2 h = __builtin_amdgcn_cvt_pkrtz(a, b);    // v_cvt_pkrtz_f16_f32
  return *(unsigned*)&h;
}
__device__ __forceinline__ float dot2(unsigned a, unsigned b, float c) {
#if __has_builtin(__builtin_amdgcn_fdot2)
  return __builtin_amdgcn_fdot2(*(f16x2*)&a, *(f16x2*)&b, c, false);  // v_dot2_f32_f16
#else
  f16x2 ha = *(f16x2*)&a, hb = *(f16x2*)&b;
  c = fmaf((float)ha[0], (float)hb[0], c);
  return fmaf((float)ha[1], (float)hb[1], c);
#endif
}

#define XBLKS (NB * (HW / 64))   // 1152 xpack blocks

// ---------------------------------------------------------------------------
// prep: (a) xpack: x [b][c][p] fp32 -> xT [b][p][c] f16 (256 B/position) via
// LDS transpose, fully coalesced both sides; (b) wpack: W -> A-frag-ordered
// f16, PER-HEAD-CONTIGUOUS otp = g*6 + s*2 + ph (24 KB hot window per head).
// ---------------------------------------------------------------------------
__global__ __launch_bounds__(256) void prep_kernel(const float* __restrict__ x,
                                                   const float* __restrict__ W,
                                                   uint4* __restrict__ xT,
                                                   uint4* __restrict__ Wf) {
  __shared__ unsigned l[64 * 67];                 // [pos][64 c-pair uints], pad 3
  const int bid = blockIdx.x;
  const int t   = threadIdx.x;
  if (bid < XBLKS) {
    const int b  = bid / (HW / 64);
    const int p0 = (bid % (HW / 64)) * 64;
    const int p  = t & 63, cg = t >> 6;           // cg: 32-channel group
    const float* xb = x + (size_t)b * CIN * HW + p0 + p;
#pragma unroll
    for (int i = 0; i < 16; ++i) {
      const int c = cg * 32 + 2 * i;
      float f0 = xb[(size_t)c * HW];              // coalesced along p
      float f1 = xb[(size_t)(c + 1) * HW];
      l[p * 67 + cg * 16 + i] = pkh2(f0, f1);
    }
    __syncthreads();
    uint4* dst = xT + ((size_t)b * HW + p0) * 16; // 16 uint4 per position
#pragma unroll
    for (int k = 0; k < 4; ++k) {
      const int u = k * 256 + t;                  // 1024 uint4 per block
      const int pos = u >> 4, ch = u & 15;
      uint4 d;
      d.x = l[pos * 67 + ch * 4 + 0];
      d.y = l[pos * 67 + ch * 4 + 1];
      d.z = l[pos * 67 + ch * 4 + 2];
      d.w = l[pos * 67 + ch * 4 + 3];
      dst[u] = d;                                 // fully coalesced 1KB/instr
    }
  } else {
    const int u = (bid - XBLKS) * 256 + t;        // 24 otp * 4 kb * 64 lanes
    const int lane = u & 63, kb = (u >> 6) & 3, otp = u >> 8;
    const int g = otp / 6, r = otp % 6, s = r >> 1, ph = r & 1;
    const int o = (s * 8 + g * 2 + ph) * 16 + (lane & 15);
    const int c0 = kb * 32 + (lane >> 4) * 8;
    const float4* w = (const float4*)(W + (size_t)o * CIN + c0);
    float4 w0 = w[0], w1 = w[1];
    uint4 rr;
    rr.x = pkh2(w0.x, w0.y); rr.y = pkh2(w0.z, w0.w);
    rr.z = pkh2(w1.x, w1.y); rr.w = pkh2(w1.z, w1.w);
    Wf[u] = rr;
  }
}

// ---------------------------------------------------------------------------
// Fused kernel: block = (b, head g, 8x16 tile), 256 threads = 4 waves.
//  Phase A: xT halo (10x18, OOB -> 0) -> f16 B-frags: one uint4 load per
//           (pos-tile, kb) -- positions 256B-contiguous, full line use.
//  GEMM (head g): 6 o-tiles x 3 pos-tiles x 4 kb mfma_f32_16x16x32_f16;
//           Q (interior) / K / V all f16 to LDS. ONE barrier.
//  Attention: thread = (pos = t>>1, dh = t&1) -- the two d-halves of a
//           position are ADJACENT LANES. Each thread does a 16-d partial QK
//           dot from its own 2 K planes (2 ds_read_b128/neighbor, no
//           duplication), then one __shfl_xor(.,1) completes the 32-d dot.
//           PV: 16 d/thread via mixed f16xf32 FMA.
//           Per-thread ds_read_b128: 2 Q + 18 K + 18 V = 38 (was 58).
// OOB halo positions have zero x-frags -> K=V=0 -> logit exactly 0, zero V
// contribution == reference zero-pad semantics, branch-free.
// LDS: Q 8KB + K 12KB + V 12KB = 32KB exactly -> 5 blocks/CU, 20 waves/CU.
// Grid 6x12x32 = 2304 blocks -> 9 blocks/CU of work; heads of one tile are
// 72 block-ids apart (0 mod 8) -> same XCD -> xT halo L2-hot across heads.
// ---------------------------------------------------------------------------
__global__ __launch_bounds__(256, 5) void fused_kernel(const uint4* __restrict__ xT,
                                                       const uint4* __restrict__ Wf,
                                                       float* __restrict__ out) {
  __shared__ uint4 qs[4 * QP];     //  8 KB f16, interior positions only
  __shared__ uint4 ks[4 * NPOS];   // 12 KB f16, halo
  __shared__ uint4 vs[4 * NPOS];   // 12 KB f16, halo

  const int z  = blockIdx.z;
  const int b  = z >> 2, g = z & 3;
  const int h0 = blockIdx.y * TH;
  const int w0 = blockIdx.x * TW;
  const int t  = threadIdx.x;
  const int wv = t >> 6, lane = t & 63;
  const int colp = lane & 15, quad = lane >> 4;

  // ---- Phase A: xT halo -> f16 B-fragments (wave owns pos-tiles wv*3..+2) ----
  uint4 frags[3][4];
  {
    const size_t xb16 = (size_t)b * HW * 16;      // uint4 units
#pragma unroll
    for (int i = 0; i < 3; ++i) {
      const int hp = (wv * 3 + i) * 16 + colp;
      const int hr = hp / HC, hc = hp - hr * HC;
      const int hh = h0 - 1 + hr, ww = w0 - 1 + hc;
      const bool ok = (hp < HP) & (hh >= 0) & (hh < HDIM) & (ww >= 0) & (ww < WDIM);
#pragma unroll
      for (int kb = 0; kb < 4; ++kb) {
        uint4 r = {0u, 0u, 0u, 0u};
        if (ok)
          r = xT[xb16 + (size_t)(hh * WDIM + ww) * 16 + kb * 4 + quad];
        frags[i][kb] = r;
      }
    }
  }

  // ---- GEMM for head g: s=0:Q, 1:K, 2:V; ph = lo/hi 16 of 32 d ----
#pragma unroll
  for (int s = 0; s < 3; ++s) {
#pragma unroll
    for (int ph = 0; ph < 2; ++ph) {
      const int otp = g * 6 + s * 2 + ph;         // per-head-contiguous Wf
      f16x8 af[4];
#pragma unroll
      for (int kb = 0; kb < 4; ++kb) {
        uint4 tmp = Wf[(otp * 4 + kb) * 64 + lane];   // L2-hot, coalesced
        af[kb] = *(f16x8*)&tmp;
      }
      const int d0 = ph * 16 + quad * 4;          // 4 consecutive d (regs 0..3)
#pragma unroll
      for (int i = 0; i < 3; ++i) {
        f32x4 acc = {0.f, 0.f, 0.f, 0.f};
#pragma unroll
        for (int kb = 0; kb < 4; ++kb)
          acc = __builtin_amdgcn_mfma_f32_16x16x32_f16(
              af[kb], *(f16x8*)&frags[i][kb], acc, 0, 0, 0);
        const int pw = (wv * 3 + i) * 16 + colp;
        uint2 st;
        st.x = pkh2(acc[0], acc[1]);
        st.y = pkh2(acc[2], acc[3]);
        if (s == 0) {
          const int hr = pw / HC, hc = pw - hr * HC;
          if (((unsigned)(hr - 1) < TH) & ((unsigned)(hc - 1) < TW)) {
            const int idx = (hr - 1) * TW + (hc - 1);
            *(uint2*)((unsigned short*)(qs + (d0 >> 3) * QP + idx)
                      + ((d0 >> 2) & 1) * 4) = st;
          }
        } else {
          uint4* dst = (s == 1) ? ks : vs;
          *(uint2*)((unsigned short*)(dst + (d0 >> 3) * NPOS + pw)
                    + ((d0 >> 2) & 1) * 4) = st;
        }
      }
    }
  }
  __syncthreads();

  // ---- attention: thread = (pos = t>>1, dh = t&1); pair = adjacent lanes ----
  const int pos = t >> 1, dh = t & 1;
  const int y = pos >> 4, xx = pos & 15;
  const int pbase = (y + 1) * HC + (xx + 1);
  const int c0 = dh * 2;                          // this thread's 2 d-planes

  unsigned qp[8];                                 // 8 x half2 = 16-d Q half
#pragma unroll
  for (int c = 0; c < 2; ++c) {
    uint4 u = qs[(c0 + c) * QP + pos];
    qp[c * 4 + 0] = u.x; qp[c * 4 + 1] = u.y;
    qp[c * 4 + 2] = u.z; qp[c * 4 + 3] = u.w;
  }

  float att[9];
#pragma unroll
  for (int nn = 0; nn < 9; ++nn) {
    const int pn = pbase + (nn / 3 - 1) * HC + (nn % 3 - 1);
    float dot = 0.0f;
#pragma unroll
    for (int c = 0; c < 2; ++c) {                 // 16-d partial (own half)
      uint4 ku = ks[(c0 + c) * NPOS + pn];
      dot = dot2(qp[c * 4 + 0], ku.x, dot);
      dot = dot2(qp[c * 4 + 1], ku.y, dot);
      dot = dot2(qp[c * 4 + 2], ku.z, dot);
      dot = dot2(qp[c * 4 + 3], ku.w, dot);
    }
    dot += __shfl_xor(dot, 1);                    // pair lane completes 32-d dot
    att[nn] = dot * 0.17677669529663687f;         // 1/sqrt(32)
  }

  float m = att[0];
#pragma unroll
  for (int nn = 1; nn < 9; ++nn) m = fmaxf(m, att[nn]);
  float ssum = 0.0f;
#pragma unroll
  for (int nn = 0; nn < 9; ++nn) { att[nn] = __expf(att[nn] - m); ssum += att[nn]; }
  const float inv = 1.0f / ssum;

  float acc[16];
#pragma unroll
  for (int i = 0; i < 16; ++i) acc[i] = 0.0f;
#pragma unroll
  for (int nn = 0; nn < 9; ++nn) {
    const float wn = att[nn] * inv;
    const int pn = pbase + (nn / 3 - 1) * HC + (nn % 3 - 1);
#pragma unroll
    for (int cc = 0; cc < 2; ++cc) {              // d-planes c0+cc
      uint4 vv = vs[(c0 + cc) * NPOS + pn];
      f16x2 h0 = *(f16x2*)&vv.x, h1 = *(f16x2*)&vv.y;
      f16x2 h2 = *(f16x2*)&vv.z, h3 = *(f16x2*)&vv.w;
      acc[cc * 8 + 0] = fmaf(wn, (float)h0[0], acc[cc * 8 + 0]);  // v_fma_mix
      acc[cc * 8 + 1] = fmaf(wn, (float)h0[1], acc[cc * 8 + 1]);
      acc[cc * 8 + 2] = fmaf(wn, (float)h1[0], acc[cc * 8 + 2]);
      acc[cc * 8 + 3] = fmaf(wn, (float)h1[1], acc[cc * 8 + 3]);
      acc[cc * 8 + 4] = fmaf(wn, (float)h2[0], acc[cc * 8 + 4]);
      acc[cc * 8 + 5] = fmaf(wn, (float)h2[1], acc[cc * 8 + 5]);
      acc[cc * 8 + 6] = fmaf(wn, (float)h3[0], acc[cc * 8 + 6]);
      acc[cc * 8 + 7] = fmaf(wn, (float)h3[1], acc[cc * 8 + 7]);
    }
  }

  // out [b][C=128][96][96]; channel = g*32 + dh*16 + i; lanes along w
  float* ob = out + ((size_t)b * CIN + (size_t)g * DHEAD + (size_t)dh * 16) * HW
            + (size_t)(h0 + y) * WDIM + (w0 + xx);
#pragma unroll
  for (int i = 0; i < 16; ++i) ob[(size_t)i * HW] = acc[i];
}

extern "C" void kernel_launch(void* const* d_in, const int* in_sizes, int n_in,
                              void* d_out, int out_size, void* d_ws, size_t ws_size,
                              hipStream_t stream) {
  (void)in_sizes; (void)n_in; (void)out_size; (void)ws_size;
  const float* x = (const float*)d_in[0];   // [8,128,96,96]
  const float* W = (const float*)d_in[1];   // [384,128]
  float* out = (float*)d_out;

  uint4* xT = (uint4*)d_ws;                              // 18.87 MB channel-last f16
  uint4* Wf = (uint4*)((char*)d_ws + (size_t)NB * HW * 256);  // 96 KB packed weights

  prep_kernel<<<XBLKS + 24, 256, 0, stream>>>(x, W, xT, Wf);
  fused_kernel<<<dim3(WDIM / TW, HDIM / TH, NB * HEADS), 256, 0, stream>>>(xT, Wf, out);
}

// Round 10
// 115.900 us; speedup vs baseline: 1.4662x; 1.0060x over previous
//
#include <hip/hip_runtime.h>

// Problem constants: x [8,128,96,96] fp32, W [384,128] fp32, out [8,128,96,96] fp32.
#define NB     8
#define CIN    128
#define HEADS  4
#define DHEAD  32
#define HDIM   96
#define WDIM   96
#define HW     9216

// Fused-kernel tile geometry. One block = (b, head, 8x16 tile), 4 waves.
#define TH     8                 // interior rows per block
#define TW     16                // interior cols per block
#define HR     (TH + 2)          // halo rows = 10
#define HC     (TW + 2)          // halo cols = 18
#define HP     (HR * HC)         // halo positions = 180
#define NT     12                // position tiles of 16 (192 >= 180, pad OOB)
#define NPOS   (NT * 16)         // 192 (no plane pad: no LDS instr crosses planes)
#define QP     (TH * TW)         // 128 interior positions

// gfx950 builtins (cvt_pkrtz / fdot2 / mfma_*_f16) use __fp16 vectors.
typedef __fp16 f16x2 __attribute__((ext_vector_type(2)));
typedef __fp16 f16x8 __attribute__((ext_vector_type(8)));
typedef float  f32x4 __attribute__((ext_vector_type(4)));

__device__ __forceinline__ unsigned pkh2(float a, float b) {
  f16x2 h = __builtin_amdgcn_cvt_pkrtz(a, b);    // v_cvt_pkrtz_f16_f32
  return *(unsigned*)&h;
}
__device__ __forceinline__ float dot2(unsigned a, unsigned b, float c) {
#if __has_builtin(__builtin_amdgcn_fdot2)
  return __builtin_amdgcn_fdot2(*(f16x2*)&a, *(f16x2*)&b, c, false);  // v_dot2_f32_f16
#else
  f16x2 ha = *(f16x2*)&a, hb = *(f16x2*)&b;
  c = fmaf((float)ha[0], (float)hb[0], c);
  return fmaf((float)ha[1], (float)hb[1], c);
#endif
}

#define XBLKS (NB * (HW / 64))   // 1152 xpack blocks

// ---------------------------------------------------------------------------
// prep: (a) xpack: x [b][c][p] fp32 -> xT [b][p][c] f16 (256 B/position) via
// LDS transpose, fully coalesced both sides; (b) wpack: W -> A-frag-ordered
// f16, PER-HEAD-CONTIGUOUS otp = g*6 + s*2 + ph (24 KB hot window per head).
// ---------------------------------------------------------------------------
__global__ __launch_bounds__(256) void prep_kernel(const float* __restrict__ x,
                                                   const float* __restrict__ W,
                                                   uint4* __restrict__ xT,
                                                   uint4* __restrict__ Wf) {
  __shared__ unsigned l[64 * 67];                 // [pos][64 c-pair uints], pad 3
  const int bid = blockIdx.x;
  const int t   = threadIdx.x;
  if (bid < XBLKS) {
    const int b  = bid / (HW / 64);
    const int p0 = (bid % (HW / 64)) * 64;
    const int p  = t & 63, cg = t >> 6;           // cg: 32-channel group
    const float* xb = x + (size_t)b * CIN * HW + p0 + p;
#pragma unroll
    for (int i = 0; i < 16; ++i) {
      const int c = cg * 32 + 2 * i;
      float f0 = xb[(size_t)c * HW];              // coalesced along p
      float f1 = xb[(size_t)(c + 1) * HW];
      l[p * 67 + cg * 16 + i] = pkh2(f0, f1);
    }
    __syncthreads();
    uint4* dst = xT + ((size_t)b * HW + p0) * 16; // 16 uint4 per position
#pragma unroll
    for (int k = 0; k < 4; ++k) {
      const int u = k * 256 + t;                  // 1024 uint4 per block
      const int pos = u >> 4, ch = u & 15;
      uint4 d;
      d.x = l[pos * 67 + ch * 4 + 0];
      d.y = l[pos * 67 + ch * 4 + 1];
      d.z = l[pos * 67 + ch * 4 + 2];
      d.w = l[pos * 67 + ch * 4 + 3];
      dst[u] = d;                                 // fully coalesced 1KB/instr
    }
  } else {
    const int u = (bid - XBLKS) * 256 + t;        // 24 otp * 4 kb * 64 lanes
    const int lane = u & 63, kb = (u >> 6) & 3, otp = u >> 8;
    const int g = otp / 6, r = otp % 6, s = r >> 1, ph = r & 1;
    const int o = (s * 8 + g * 2 + ph) * 16 + (lane & 15);
    const int c0 = kb * 32 + (lane >> 4) * 8;
    const float4* w = (const float4*)(W + (size_t)o * CIN + c0);
    float4 w0 = w[0], w1 = w[1];
    uint4 rr;
    rr.x = pkh2(w0.x, w0.y); rr.y = pkh2(w0.z, w0.w);
    rr.z = pkh2(w1.x, w1.y); rr.w = pkh2(w1.z, w1.w);
    Wf[u] = rr;
  }
}

// ---------------------------------------------------------------------------
// Fused kernel: block = (b, head g, 8x16 tile), 256 threads = 4 waves.
//  Phase A: xT halo (10x18, OOB -> 0) -> f16 B-frags: one uint4 load per
//           (pos-tile, kb) -- positions 256B-contiguous, full line use.
//  GEMM (head g): 6 o-tiles x 3 pos-tiles x 4 kb mfma_f32_16x16x32_f16;
//           Q (interior, skips fully-exterior tiles 0/11) / K / V f16 to LDS.
//           ONE barrier.
//  Attention: thread = (pos = t>>1, dh = t&1) -- d-halves in ADJACENT LANES;
//           16-d partial QK dot (2 ds_read_b128/neighbor), __shfl_xor(.,1)
//           completes the 32-d dot. PV: 16 d/thread via mixed f16xf32 FMA.
// OOB halo positions have zero x-frags -> K=V=0 -> logit exactly 0, zero V
// contribution == reference zero-pad semantics, branch-free.
// LDS: Q 8KB + K 12KB + V 12KB = 32KB exactly -> LDS alone allows 5 blocks/CU.
// NO min-waves bound: let the allocator take the VGPRs it needs (suspected
// spill at the (256,5) cap ~96-102 was the invariant throttle r7-r9).
// Grid 6x12x32 = 2304 blocks; heads of one tile are 72 ids apart (0 mod 8)
// -> same XCD -> xT halo L2-hot across heads.
// ---------------------------------------------------------------------------
__global__ __launch_bounds__(256) void fused_kernel(const uint4* __restrict__ xT,
                                                    const uint4* __restrict__ Wf,
                                                    float* __restrict__ out) {
  __shared__ uint4 qs[4 * QP];     //  8 KB f16, interior positions only
  __shared__ uint4 ks[4 * NPOS];   // 12 KB f16, halo
  __shared__ uint4 vs[4 * NPOS];   // 12 KB f16, halo

  const int z  = blockIdx.z;
  const int b  = z >> 2, g = z & 3;
  const int h0 = blockIdx.y * TH;
  const int w0 = blockIdx.x * TW;
  const int t  = threadIdx.x;
  const int wv = t >> 6, lane = t & 63;
  const int colp = lane & 15, quad = lane >> 4;

  // ---- Phase A: xT halo -> f16 B-fragments (wave owns pos-tiles wv*3..+2) ----
  uint4 frags[3][4];
  {
    const size_t xb16 = (size_t)b * HW * 16;      // uint4 units
#pragma unroll
    for (int i = 0; i < 3; ++i) {
      const int hp = (wv * 3 + i) * 16 + colp;
      const int hr = hp / HC, hc = hp - hr * HC;
      const int hh = h0 - 1 + hr, ww = w0 - 1 + hc;
      const bool ok = (hp < HP) & (hh >= 0) & (hh < HDIM) & (ww >= 0) & (ww < WDIM);
#pragma unroll
      for (int kb = 0; kb < 4; ++kb) {
        uint4 r = {0u, 0u, 0u, 0u};
        if (ok)
          r = xT[xb16 + (size_t)(hh * WDIM + ww) * 16 + kb * 4 + quad];
        frags[i][kb] = r;
      }
    }
  }

  // ---- GEMM for head g: s=0:Q, 1:K, 2:V; ph = lo/hi 16 of 32 d ----
#pragma unroll
  for (int s = 0; s < 3; ++s) {
#pragma unroll
    for (int ph = 0; ph < 2; ++ph) {
      const int otp = g * 6 + s * 2 + ph;         // per-head-contiguous Wf
      f16x8 af[4];
#pragma unroll
      for (int kb = 0; kb < 4; ++kb) {
        uint4 tmp = Wf[(otp * 4 + kb) * 64 + lane];   // L2-hot, coalesced
        af[kb] = *(f16x8*)&tmp;
      }
      const int d0 = ph * 16 + quad * 4;          // 4 consecutive d (regs 0..3)
#pragma unroll
      for (int i = 0; i < 3; ++i) {
        const int tile = wv * 3 + i;
        // Q: tiles 0 (all halo-row 0) and 11 (halo-row 9 + pad) are fully
        // exterior -> no interior Q positions -> skip their MFMAs entirely.
        if (s == 0 && (tile == 0 || tile == 11)) continue;
        f32x4 acc = {0.f, 0.f, 0.f, 0.f};
#pragma unroll
        for (int kb = 0; kb < 4; ++kb)
          acc = __builtin_amdgcn_mfma_f32_16x16x32_f16(
              af[kb], *(f16x8*)&frags[i][kb], acc, 0, 0, 0);
        const int pw = tile * 16 + colp;
        uint2 st;
        st.x = pkh2(acc[0], acc[1]);
        st.y = pkh2(acc[2], acc[3]);
        if (s == 0) {
          const int hr = pw / HC, hc = pw - hr * HC;
          if (((unsigned)(hr - 1) < TH) & ((unsigned)(hc - 1) < TW)) {
            const int idx = (hr - 1) * TW + (hc - 1);
            *(uint2*)((unsigned short*)(qs + (d0 >> 3) * QP + idx)
                      + ((d0 >> 2) & 1) * 4) = st;
          }
        } else {
          uint4* dst = (s == 1) ? ks : vs;
          *(uint2*)((unsigned short*)(dst + (d0 >> 3) * NPOS + pw)
                    + ((d0 >> 2) & 1) * 4) = st;
        }
      }
    }
  }
  __syncthreads();

  // ---- attention: thread = (pos = t>>1, dh = t&1); pair = adjacent lanes ----
  const int pos = t >> 1, dh = t & 1;
  const int y = pos >> 4, xx = pos & 15;
  const int pbase = (y + 1) * HC + (xx + 1);
  const int c0 = dh * 2;                          // this thread's 2 d-planes

  unsigned qp[8];                                 // 8 x half2 = 16-d Q half
#pragma unroll
  for (int c = 0; c < 2; ++c) {
    uint4 u = qs[(c0 + c) * QP + pos];
    qp[c * 4 + 0] = u.x; qp[c * 4 + 1] = u.y;
    qp[c * 4 + 2] = u.z; qp[c * 4 + 3] = u.w;
  }

  float att[9];
#pragma unroll
  for (int nn = 0; nn < 9; ++nn) {
    const int pn = pbase + (nn / 3 - 1) * HC + (nn % 3 - 1);
    float dot = 0.0f;
#pragma unroll
    for (int c = 0; c < 2; ++c) {                 // 16-d partial (own half)
      uint4 ku = ks[(c0 + c) * NPOS + pn];
      dot = dot2(qp[c * 4 + 0], ku.x, dot);
      dot = dot2(qp[c * 4 + 1], ku.y, dot);
      dot = dot2(qp[c * 4 + 2], ku.z, dot);
      dot = dot2(qp[c * 4 + 3], ku.w, dot);
    }
    dot += __shfl_xor(dot, 1);                    // pair lane completes 32-d dot
    att[nn] = dot * 0.17677669529663687f;         // 1/sqrt(32)
  }

  float m = att[0];
#pragma unroll
  for (int nn = 1; nn < 9; ++nn) m = fmaxf(m, att[nn]);
  float ssum = 0.0f;
#pragma unroll
  for (int nn = 0; nn < 9; ++nn) { att[nn] = __expf(att[nn] - m); ssum += att[nn]; }
  const float inv = 1.0f / ssum;

  float acc[16];
#pragma unroll
  for (int i = 0; i < 16; ++i) acc[i] = 0.0f;
#pragma unroll
  for (int nn = 0; nn < 9; ++nn) {
    const float wn = att[nn] * inv;
    const int pn = pbase + (nn / 3 - 1) * HC + (nn % 3 - 1);
#pragma unroll
    for (int cc = 0; cc < 2; ++cc) {              // d-planes c0+cc
      uint4 vv = vs[(c0 + cc) * NPOS + pn];
      f16x2 h0 = *(f16x2*)&vv.x, h1 = *(f16x2*)&vv.y;
      f16x2 h2 = *(f16x2*)&vv.z, h3 = *(f16x2*)&vv.w;
      acc[cc * 8 + 0] = fmaf(wn, (float)h0[0], acc[cc * 8 + 0]);  // v_fma_mix
      acc[cc * 8 + 1] = fmaf(wn, (float)h0[1], acc[cc * 8 + 1]);
      acc[cc * 8 + 2] = fmaf(wn, (float)h1[0], acc[cc * 8 + 2]);
      acc[cc * 8 + 3] = fmaf(wn, (float)h1[1], acc[cc * 8 + 3]);
      acc[cc * 8 + 4] = fmaf(wn, (float)h2[0], acc[cc * 8 + 4]);
      acc[cc * 8 + 5] = fmaf(wn, (float)h2[1], acc[cc * 8 + 5]);
      acc[cc * 8 + 6] = fmaf(wn, (float)h3[0], acc[cc * 8 + 6]);
      acc[cc * 8 + 7] = fmaf(wn, (float)h3[1], acc[cc * 8 + 7]);
    }
  }

  // out [b][C=128][96][96]; channel = g*32 + dh*16 + i; lanes along w
  float* ob = out + ((size_t)b * CIN + (size_t)g * DHEAD + (size_t)dh * 16) * HW
            + (size_t)(h0 + y) * WDIM + (w0 + xx);
#pragma unroll
  for (int i = 0; i < 16; ++i) ob[(size_t)i * HW] = acc[i];
}

extern "C" void kernel_launch(void* const* d_in, const int* in_sizes, int n_in,
                              void* d_out, int out_size, void* d_ws, size_t ws_size,
                              hipStream_t stream) {
  (void)in_sizes; (void)n_in; (void)out_size; (void)ws_size;
  const float* x = (const float*)d_in[0];   // [8,128,96,96]
  const float* W = (const float*)d_in[1];   // [384,128]
  float* out = (float*)d_out;

  uint4* xT = (uint4*)d_ws;                              // 18.87 MB channel-last f16
  uint4* Wf = (uint4*)((char*)d_ws + (size_t)NB * HW * 256);  // 96 KB packed weights

  prep_kernel<<<XBLKS + 24, 256, 0, stream>>>(x, W, xT, Wf);
  fused_kernel<<<dim3(WDIM / TW, HDIM / TH, NB * HEADS), 256, 0, stream>>>(xT, Wf, out);
}

// Round 11
// 114.093 us; speedup vs baseline: 1.4894x; 1.0158x over previous
//
#include <hip/hip_runtime.h>

// Problem constants: x [8,128,96,96] fp32, W [384,128] fp32, out [8,128,96,96] fp32.
#define NB     8
#define CIN    128
#define HEADS  4
#define DHEAD  32
#define HDIM   96
#define WDIM   96
#define HW     9216

// Fused-kernel tile geometry. One block = (b, head, 8x16 tile), 4 waves.
#define TH     8                 // interior rows per block
#define TW     16                // interior cols per block
#define HR     (TH + 2)          // halo rows = 10
#define HC     (TW + 2)          // halo cols = 18
#define HP     (HR * HC)         // halo positions = 180
#define NT     12                // position tiles of 16 (192 >= 180, pad OOB)
#define NPOS   (NT * 16)         // 192 (no plane pad: no LDS instr crosses planes)
#define QP     (TH * TW)         // 128 interior positions

// gfx950 builtins (cvt_pkrtz / fdot2 / mfma_*_f16) use __fp16 vectors.
typedef __fp16 f16x2 __attribute__((ext_vector_type(2)));
typedef __fp16 f16x8 __attribute__((ext_vector_type(8)));
typedef float  f32x4 __attribute__((ext_vector_type(4)));

__device__ __forceinline__ unsigned pkh2(float a, float b) {
  f16x2 h = __builtin_amdgcn_cvt_pkrtz(a, b);    // v_cvt_pkrtz_f16_f32
  return *(unsigned*)&h;
}
__device__ __forceinline__ float dot2(unsigned a, unsigned b, float c) {
#if __has_builtin(__builtin_amdgcn_fdot2)
  return __builtin_amdgcn_fdot2(*(f16x2*)&a, *(f16x2*)&b, c, false);  // v_dot2_f32_f16
#else
  f16x2 ha = *(f16x2*)&a, hb = *(f16x2*)&b;
  c = fmaf((float)ha[0], (float)hb[0], c);
  return fmaf((float)ha[1], (float)hb[1], c);
#endif
}

#define XBLKS (NB * (HW / 64))   // 1152 xpack blocks

// ---------------------------------------------------------------------------
// prep: (a) xpack: x [b][c][p] fp32 -> xT [b][p][c] f16 (256 B/position) via
// LDS transpose, fully coalesced both sides; (b) wpack: W -> A-frag-ordered
// f16, PER-HEAD-CONTIGUOUS otp = g*6 + s*2 + ph (24 KB hot window per head).
// ---------------------------------------------------------------------------
__global__ __launch_bounds__(256) void prep_kernel(const float* __restrict__ x,
                                                   const float* __restrict__ W,
                                                   uint4* __restrict__ xT,
                                                   uint4* __restrict__ Wf) {
  __shared__ unsigned l[64 * 67];                 // [pos][64 c-pair uints], pad 3
  const int bid = blockIdx.x;
  const int t   = threadIdx.x;
  if (bid < XBLKS) {
    const int b  = bid / (HW / 64);
    const int p0 = (bid % (HW / 64)) * 64;
    const int p  = t & 63, cg = t >> 6;           // cg: 32-channel group
    const float* xb = x + (size_t)b * CIN * HW + p0 + p;
#pragma unroll
    for (int i = 0; i < 16; ++i) {
      const int c = cg * 32 + 2 * i;
      float f0 = xb[(size_t)c * HW];              // coalesced along p
      float f1 = xb[(size_t)(c + 1) * HW];
      l[p * 67 + cg * 16 + i] = pkh2(f0, f1);
    }
    __syncthreads();
    uint4* dst = xT + ((size_t)b * HW + p0) * 16; // 16 uint4 per position
#pragma unroll
    for (int k = 0; k < 4; ++k) {
      const int u = k * 256 + t;                  // 1024 uint4 per block
      const int pos = u >> 4, ch = u & 15;
      uint4 d;
      d.x = l[pos * 67 + ch * 4 + 0];
      d.y = l[pos * 67 + ch * 4 + 1];
      d.z = l[pos * 67 + ch * 4 + 2];
      d.w = l[pos * 67 + ch * 4 + 3];
      dst[u] = d;                                 // fully coalesced 1KB/instr
    }
  } else {
    const int u = (bid - XBLKS) * 256 + t;        // 24 otp * 4 kb * 64 lanes
    const int lane = u & 63, kb = (u >> 6) & 3, otp = u >> 8;
    const int g = otp / 6, r = otp % 6, s = r >> 1, ph = r & 1;
    const int o = (s * 8 + g * 2 + ph) * 16 + (lane & 15);
    const int c0 = kb * 32 + (lane >> 4) * 8;
    const float4* w = (const float4*)(W + (size_t)o * CIN + c0);
    float4 w0 = w[0], w1 = w[1];
    uint4 rr;
    rr.x = pkh2(w0.x, w0.y); rr.y = pkh2(w0.z, w0.w);
    rr.z = pkh2(w1.x, w1.y); rr.w = pkh2(w1.z, w1.w);
    Wf[u] = rr;
  }
}

// ---------------------------------------------------------------------------
// Fused kernel: block = (b, head g, 8x16 tile), 256 threads = 4 waves.
//  Phase A: xT halo (10x18, OOB -> 0) -> f16 B-frags, then PINNED in VGPRs
//           via empty asm (r10 showed VGPR_Count=48: the allocator was
//           REMATERIALIZING the 12 frag loads inside the GEMM loop, ~6x
//           redundant L2 traffic + exposed latency -- the invariant throttle).
//  GEMM (head g): 6 o-tiles x 3 pos-tiles x 4 kb mfma_f32_16x16x32_f16;
//           Q (interior, skip exterior tiles 0/11) / K / V f16 to LDS. 1 barrier.
//  Attention: thread = (pos = t>>1, dh = t&1), d-halves in adjacent lanes;
//           BATCHED: all 18 K ds_read_b128 -> kreg, then dot chains;
//           __shfl_xor(.,1) completes 32-d dot; all 18 V reads -> vreg,
//           then PV via mixed f16xf32 FMA (16 d/thread).
// OOB halo positions have zero x-frags -> K=V=0 -> logit exactly 0, zero V
// contribution == reference zero-pad semantics, branch-free.
// LDS: Q 8KB + K 12KB + V 12KB = 32KB -> 5 blocks/CU; (256,5) caps VGPR at
// 102 (live set ~85-100 fits without spill or remat).
// ---------------------------------------------------------------------------
__global__ __launch_bounds__(256, 5) void fused_kernel(const uint4* __restrict__ xT,
                                                       const uint4* __restrict__ Wf,
                                                       float* __restrict__ out) {
  __shared__ uint4 qs[4 * QP];     //  8 KB f16, interior positions only
  __shared__ uint4 ks[4 * NPOS];   // 12 KB f16, halo
  __shared__ uint4 vs[4 * NPOS];   // 12 KB f16, halo

  const int z  = blockIdx.z;
  const int b  = z >> 2, g = z & 3;
  const int h0 = blockIdx.y * TH;
  const int w0 = blockIdx.x * TW;
  const int t  = threadIdx.x;
  const int wv = t >> 6, lane = t & 63;
  const int colp = lane & 15, quad = lane >> 4;

  // ---- Phase A: xT halo -> f16 B-fragments (wave owns pos-tiles wv*3..+2) ----
  uint4 frags[3][4];
  {
    const size_t xb16 = (size_t)b * HW * 16;      // uint4 units
#pragma unroll
    for (int i = 0; i < 3; ++i) {
      const int hp = (wv * 3 + i) * 16 + colp;
      const int hr = hp / HC, hc = hp - hr * HC;
      const int hh = h0 - 1 + hr, ww = w0 - 1 + hc;
      const bool ok = (hp < HP) & (hh >= 0) & (hh < HDIM) & (ww >= 0) & (ww < WDIM);
#pragma unroll
      for (int kb = 0; kb < 4; ++kb) {
        uint4 r = {0u, 0u, 0u, 0u};
        if (ok)
          r = xT[xb16 + (size_t)(hh * WDIM + ww) * 16 + kb * 4 + quad];
        frags[i][kb] = r;
      }
    }
  }
  // PIN the fragments: opaque redefinition -> compiler cannot rematerialize
  // the global loads past this point (rule-17 keep-alive idiom).
#pragma unroll
  for (int i = 0; i < 3; ++i)
#pragma unroll
    for (int kb = 0; kb < 4; ++kb)
      asm volatile("" : "+v"(frags[i][kb].x), "+v"(frags[i][kb].y),
                        "+v"(frags[i][kb].z), "+v"(frags[i][kb].w));

  // ---- GEMM for head g: s=0:Q, 1:K, 2:V; ph = lo/hi 16 of 32 d ----
#pragma unroll
  for (int s = 0; s < 3; ++s) {
#pragma unroll
    for (int ph = 0; ph < 2; ++ph) {
      const int otp = g * 6 + s * 2 + ph;         // per-head-contiguous Wf
      f16x8 af[4];
#pragma unroll
      for (int kb = 0; kb < 4; ++kb) {
        uint4 tmp = Wf[(otp * 4 + kb) * 64 + lane];   // L2-hot, coalesced
        af[kb] = *(f16x8*)&tmp;
      }
      const int d0 = ph * 16 + quad * 4;          // 4 consecutive d (regs 0..3)
#pragma unroll
      for (int i = 0; i < 3; ++i) {
        const int tile = wv * 3 + i;
        // Q: tiles 0 and 11 have no interior positions -> skip their MFMAs.
        if (s == 0 && (tile == 0 || tile == 11)) continue;
        f32x4 acc = {0.f, 0.f, 0.f, 0.f};
#pragma unroll
        for (int kb = 0; kb < 4; ++kb)
          acc = __builtin_amdgcn_mfma_f32_16x16x32_f16(
              af[kb], *(f16x8*)&frags[i][kb], acc, 0, 0, 0);
        const int pw = tile * 16 + colp;
        uint2 st;
        st.x = pkh2(acc[0], acc[1]);
        st.y = pkh2(acc[2], acc[3]);
        if (s == 0) {
          const int hr = pw / HC, hc = pw - hr * HC;
          if (((unsigned)(hr - 1) < TH) & ((unsigned)(hc - 1) < TW)) {
            const int idx = (hr - 1) * TW + (hc - 1);
            *(uint2*)((unsigned short*)(qs + (d0 >> 3) * QP + idx)
                      + ((d0 >> 2) & 1) * 4) = st;
          }
        } else {
          uint4* dst = (s == 1) ? ks : vs;
          *(uint2*)((unsigned short*)(dst + (d0 >> 3) * NPOS + pw)
                    + ((d0 >> 2) & 1) * 4) = st;
        }
      }
    }
  }
  __syncthreads();

  // ---- attention: thread = (pos = t>>1, dh = t&1); pair = adjacent lanes ----
  const int pos = t >> 1, dh = t & 1;
  const int y = pos >> 4, xx = pos & 15;
  const int pbase = (y + 1) * HC + (xx + 1);
  const int c0 = dh * 2;                          // this thread's 2 d-planes

  unsigned qp[8];                                 // 8 x half2 = 16-d Q half
#pragma unroll
  for (int c = 0; c < 2; ++c) {
    uint4 u = qs[(c0 + c) * QP + pos];
    qp[c * 4 + 0] = u.x; qp[c * 4 + 1] = u.y;
    qp[c * 4 + 2] = u.z; qp[c * 4 + 3] = u.w;
  }

  // Batch ALL K reads (18 ds_read_b128) -> one latency exposure.
  uint4 kreg[9][2];
#pragma unroll
  for (int nn = 0; nn < 9; ++nn) {
    const int pn = pbase + (nn / 3 - 1) * HC + (nn % 3 - 1);
    kreg[nn][0] = ks[(c0 + 0) * NPOS + pn];
    kreg[nn][1] = ks[(c0 + 1) * NPOS + pn];
  }

  float att[9];
#pragma unroll
  for (int nn = 0; nn < 9; ++nn) {
    float dot = 0.0f;
#pragma unroll
    for (int c = 0; c < 2; ++c) {                 // 16-d partial (own half)
      dot = dot2(qp[c * 4 + 0], kreg[nn][c].x, dot);
      dot = dot2(qp[c * 4 + 1], kreg[nn][c].y, dot);
      dot = dot2(qp[c * 4 + 2], kreg[nn][c].z, dot);
      dot = dot2(qp[c * 4 + 3], kreg[nn][c].w, dot);
    }
    dot += __shfl_xor(dot, 1);                    // pair lane completes 32-d dot
    att[nn] = dot * 0.17677669529663687f;         // 1/sqrt(32)
  }

  float m = att[0];
#pragma unroll
  for (int nn = 1; nn < 9; ++nn) m = fmaxf(m, att[nn]);
  float ssum = 0.0f;
#pragma unroll
  for (int nn = 0; nn < 9; ++nn) { att[nn] = __expf(att[nn] - m); ssum += att[nn]; }
  const float inv = 1.0f / ssum;

  // Batch ALL V reads (18 ds_read_b128), then PV from regs.
  uint4 vreg[9][2];
#pragma unroll
  for (int nn = 0; nn < 9; ++nn) {
    const int pn = pbase + (nn / 3 - 1) * HC + (nn % 3 - 1);
    vreg[nn][0] = vs[(c0 + 0) * NPOS + pn];
    vreg[nn][1] = vs[(c0 + 1) * NPOS + pn];
  }

  float acc[16];
#pragma unroll
  for (int i = 0; i < 16; ++i) acc[i] = 0.0f;
#pragma unroll
  for (int nn = 0; nn < 9; ++nn) {
    const float wn = att[nn] * inv;
#pragma unroll
    for (int cc = 0; cc < 2; ++cc) {              // d-planes c0+cc
      uint4 vv = vreg[nn][cc];
      f16x2 h0 = *(f16x2*)&vv.x, h1 = *(f16x2*)&vv.y;
      f16x2 h2 = *(f16x2*)&vv.z, h3 = *(f16x2*)&vv.w;
      acc[cc * 8 + 0] = fmaf(wn, (float)h0[0], acc[cc * 8 + 0]);  // v_fma_mix
      acc[cc * 8 + 1] = fmaf(wn, (float)h0[1], acc[cc * 8 + 1]);
      acc[cc * 8 + 2] = fmaf(wn, (float)h1[0], acc[cc * 8 + 2]);
      acc[cc * 8 + 3] = fmaf(wn, (float)h1[1], acc[cc * 8 + 3]);
      acc[cc * 8 + 4] = fmaf(wn, (float)h2[0], acc[cc * 8 + 4]);
      acc[cc * 8 + 5] = fmaf(wn, (float)h2[1], acc[cc * 8 + 5]);
      acc[cc * 8 + 6] = fmaf(wn, (float)h3[0], acc[cc * 8 + 6]);
      acc[cc * 8 + 7] = fmaf(wn, (float)h3[1], acc[cc * 8 + 7]);
    }
  }

  // out [b][C=128][96][96]; channel = g*32 + dh*16 + i; lanes along w
  float* ob = out + ((size_t)b * CIN + (size_t)g * DHEAD + (size_t)dh * 16) * HW
            + (size_t)(h0 + y) * WDIM + (w0 + xx);
#pragma unroll
  for (int i = 0; i < 16; ++i) ob[(size_t)i * HW] = acc[i];
}

extern "C" void kernel_launch(void* const* d_in, const int* in_sizes, int n_in,
                              void* d_out, int out_size, void* d_ws, size_t ws_size,
                              hipStream_t stream) {
  (void)in_sizes; (void)n_in; (void)out_size; (void)ws_size;
  const float* x = (const float*)d_in[0];   // [8,128,96,96]
  const float* W = (const float*)d_in[1];   // [384,128]
  float* out = (float*)d_out;

  uint4* xT = (uint4*)d_ws;                              // 18.87 MB channel-last f16
  uint4* Wf = (uint4*)((char*)d_ws + (size_t)NB * HW * 256);  // 96 KB packed weights

  prep_kernel<<<XBLKS + 24, 256, 0, stream>>>(x, W, xT, Wf);
  fused_kernel<<<dim3(WDIM / TW, HDIM / TH, NB * HEADS), 256, 0, stream>>>(xT, Wf, out);
}

// Round 12
// 113.990 us; speedup vs baseline: 1.4907x; 1.0009x over previous
//
#include <hip/hip_runtime.h>

// Problem constants: x [8,128,96,96] fp32, W [384,128] fp32, out [8,128,96,96] fp32.
#define NB     8
#define CIN    128
#define HEADS  4
#define DHEAD  32
#define HDIM   96
#define WDIM   96
#define HW     9216

// Fused-kernel tile geometry. One block = (b, head, 8x16 tile), 4 waves.
#define TH     8                 // interior rows per block
#define TW     16                // interior cols per block
#define HR     (TH + 2)          // halo rows = 10
#define HC     (TW + 2)          // halo cols = 18
#define HP     (HR * HC)         // halo positions = 180
#define NT     12                // position tiles of 16 (192 >= 180, pad OOB)
#define NPOS   (NT * 16)         // 192 (no plane pad: no LDS instr crosses planes)
#define QP     (TH * TW)         // 128 interior positions

// gfx950 builtins (cvt_pkrtz / fdot2 / mfma_*_f16) use __fp16 vectors.
typedef __fp16 f16x2 __attribute__((ext_vector_type(2)));
typedef __fp16 f16x8 __attribute__((ext_vector_type(8)));
typedef float  f32x4 __attribute__((ext_vector_type(4)));

__device__ __forceinline__ unsigned pkh2(float a, float b) {
  f16x2 h = __builtin_amdgcn_cvt_pkrtz(a, b);    // v_cvt_pkrtz_f16_f32
  return *(unsigned*)&h;
}
__device__ __forceinline__ float dot2(unsigned a, unsigned b, float c) {
#if __has_builtin(__builtin_amdgcn_fdot2)
  return __builtin_amdgcn_fdot2(*(f16x2*)&a, *(f16x2*)&b, c, false);  // v_dot2_f32_f16
#else
  f16x2 ha = *(f16x2*)&a, hb = *(f16x2*)&b;
  c = fmaf((float)ha[0], (float)hb[0], c);
  return fmaf((float)ha[1], (float)hb[1], c);
#endif
}

#define XBLKS (NB * (HW / 64))   // 1152 xpack blocks

// ---------------------------------------------------------------------------
// prep: (a) xpack: x [b][c][p] fp32 -> xT [b][p][c] f16 (256 B/position) via
// LDS transpose, fully coalesced both sides; (b) wpack: W -> A-frag-ordered
// f16, PER-HEAD-CONTIGUOUS otp = g*6 + s*2 + ph (24 KB hot window per head).
// ---------------------------------------------------------------------------
__global__ __launch_bounds__(256) void prep_kernel(const float* __restrict__ x,
                                                   const float* __restrict__ W,
                                                   uint4* __restrict__ xT,
                                                   uint4* __restrict__ Wf) {
  __shared__ unsigned l[64 * 67];                 // [pos][64 c-pair uints], pad 3
  const int bid = blockIdx.x;
  const int t   = threadIdx.x;
  if (bid < XBLKS) {
    const int b  = bid / (HW / 64);
    const int p0 = (bid % (HW / 64)) * 64;
    const int p  = t & 63, cg = t >> 6;           // cg: 32-channel group
    const float* xb = x + (size_t)b * CIN * HW + p0 + p;
#pragma unroll
    for (int i = 0; i < 16; ++i) {
      const int c = cg * 32 + 2 * i;
      float f0 = xb[(size_t)c * HW];              // coalesced along p
      float f1 = xb[(size_t)(c + 1) * HW];
      l[p * 67 + cg * 16 + i] = pkh2(f0, f1);
    }
    __syncthreads();
    uint4* dst = xT + ((size_t)b * HW + p0) * 16; // 16 uint4 per position
#pragma unroll
    for (int k = 0; k < 4; ++k) {
      const int u = k * 256 + t;                  // 1024 uint4 per block
      const int pos = u >> 4, ch = u & 15;
      uint4 d;
      d.x = l[pos * 67 + ch * 4 + 0];
      d.y = l[pos * 67 + ch * 4 + 1];
      d.z = l[pos * 67 + ch * 4 + 2];
      d.w = l[pos * 67 + ch * 4 + 3];
      dst[u] = d;                                 // fully coalesced 1KB/instr
    }
  } else {
    const int u = (bid - XBLKS) * 256 + t;        // 24 otp * 4 kb * 64 lanes
    const int lane = u & 63, kb = (u >> 6) & 3, otp = u >> 8;
    const int g = otp / 6, r = otp % 6, s = r >> 1, ph = r & 1;
    const int o = (s * 8 + g * 2 + ph) * 16 + (lane & 15);
    const int c0 = kb * 32 + (lane >> 4) * 8;
    const float4* w = (const float4*)(W + (size_t)o * CIN + c0);
    float4 w0 = w[0], w1 = w[1];
    uint4 rr;
    rr.x = pkh2(w0.x, w0.y); rr.y = pkh2(w0.z, w0.w);
    rr.z = pkh2(w1.x, w1.y); rr.w = pkh2(w1.z, w1.w);
    Wf[u] = rr;
  }
}

// ---------------------------------------------------------------------------
// Fused kernel: block = (b, head g, 8x16 tile), 256 threads = 4 waves.
//  Phase A: xT halo (10x18, OOB -> 0) -> f16 B-frags, PINNED via empty asm
//           (blocks the r10 remat pathology).
//  GEMM (head g): 3 groups (s=Q,K,V), each: 8 Wf uint4 (both ph halves,
//           prefetched one group ahead so L2 latency hides under the previous
//           group's 24 MFMAs) -> mfma_f32_16x16x32_f16 x 24 -> f16 LDS.
//           Serialized L2 exposures: 6 (r11) -> ~1.
//  Attention: thread = (pos = t>>1, dh = t&1), d-halves in adjacent lanes;
//           batched K reads -> 16-d partial dots -> __shfl_xor(.,1);
//           batched V reads -> PV via mixed f16xf32 FMA (16 d/thread).
// OOB halo positions have zero x-frags -> K=V=0 -> logit exactly 0, zero V
// contribution == reference zero-pad semantics, branch-free.
// LDS: Q 8KB + K 12KB + V 12KB = 32KB. No min-waves bound: VGPR (~120-135)
// sets residency (~4 blocks/CU); pin prevents remat at that pressure.
// ---------------------------------------------------------------------------
__global__ __launch_bounds__(256) void fused_kernel(const uint4* __restrict__ xT,
                                                    const uint4* __restrict__ Wf,
                                                    float* __restrict__ out) {
  __shared__ uint4 qs[4 * QP];     //  8 KB f16, interior positions only
  __shared__ uint4 ks[4 * NPOS];   // 12 KB f16, halo
  __shared__ uint4 vs[4 * NPOS];   // 12 KB f16, halo

  const int z  = blockIdx.z;
  const int b  = z >> 2, g = z & 3;
  const int h0 = blockIdx.y * TH;
  const int w0 = blockIdx.x * TW;
  const int t  = threadIdx.x;
  const int wv = t >> 6, lane = t & 63;
  const int colp = lane & 15, quad = lane >> 4;

  // ---- Phase A: xT halo -> f16 B-fragments (wave owns pos-tiles wv*3..+2) ----
  uint4 frags[3][4];
  {
    const size_t xb16 = (size_t)b * HW * 16;      // uint4 units
#pragma unroll
    for (int i = 0; i < 3; ++i) {
      const int hp = (wv * 3 + i) * 16 + colp;
      const int hr = hp / HC, hc = hp - hr * HC;
      const int hh = h0 - 1 + hr, ww = w0 - 1 + hc;
      const bool ok = (hp < HP) & (hh >= 0) & (hh < HDIM) & (ww >= 0) & (ww < WDIM);
#pragma unroll
      for (int kb = 0; kb < 4; ++kb) {
        uint4 r = {0u, 0u, 0u, 0u};
        if (ok)
          r = xT[xb16 + (size_t)(hh * WDIM + ww) * 16 + kb * 4 + quad];
        frags[i][kb] = r;
      }
    }
  }
  // PIN: opaque redefinition -> no rematerialization of the halo loads.
#pragma unroll
  for (int i = 0; i < 3; ++i)
#pragma unroll
    for (int kb = 0; kb < 4; ++kb)
      asm volatile("" : "+v"(frags[i][kb].x), "+v"(frags[i][kb].y),
                        "+v"(frags[i][kb].z), "+v"(frags[i][kb].w));

  // ---- GEMM: 3 groups (s), both ph halves per group, af prefetch 1 ahead ----
  const uint4* wfg = Wf + (g * 6) * 4 * 64 + lane;   // head window base
  uint4 afc[8];                                      // current group's af
#pragma unroll
  for (int j = 0; j < 8; ++j) afc[j] = wfg[j * 64];  // group s=0 (ph0+ph1)

#pragma unroll
  for (int s = 0; s < 3; ++s) {
    uint4 afn[8];
    if (s < 2) {
#pragma unroll
      for (int j = 0; j < 8; ++j) afn[j] = wfg[((s + 1) * 8 + j) * 64];
    }
#pragma unroll
    for (int ph = 0; ph < 2; ++ph) {
      const int d0 = ph * 16 + quad * 4;          // 4 consecutive d (regs 0..3)
#pragma unroll
      for (int i = 0; i < 3; ++i) {
        const int tile = wv * 3 + i;
        if (s == 0 && (tile == 0 || tile == 11)) continue;  // no interior Q
        f32x4 acc = {0.f, 0.f, 0.f, 0.f};
#pragma unroll
        for (int kb = 0; kb < 4; ++kb)
          acc = __builtin_amdgcn_mfma_f32_16x16x32_f16(
              *(f16x8*)&afc[ph * 4 + kb], *(f16x8*)&frags[i][kb], acc, 0, 0, 0);
        const int pw = tile * 16 + colp;
        uint2 st;
        st.x = pkh2(acc[0], acc[1]);
        st.y = pkh2(acc[2], acc[3]);
        if (s == 0) {
          const int hr = pw / HC, hc = pw - hr * HC;
          if (((unsigned)(hr - 1) < TH) & ((unsigned)(hc - 1) < TW)) {
            const int idx = (hr - 1) * TW + (hc - 1);
            *(uint2*)((unsigned short*)(qs + (d0 >> 3) * QP + idx)
                      + ((d0 >> 2) & 1) * 4) = st;
          }
        } else {
          uint4* dst = (s == 1) ? ks : vs;
          *(uint2*)((unsigned short*)(dst + (d0 >> 3) * NPOS + pw)
                    + ((d0 >> 2) & 1) * 4) = st;
        }
      }
    }
    if (s < 2) {
#pragma unroll
      for (int j = 0; j < 8; ++j) afc[j] = afn[j];
    }
  }
  __syncthreads();

  // ---- attention: thread = (pos = t>>1, dh = t&1); pair = adjacent lanes ----
  const int pos = t >> 1, dh = t & 1;
  const int y = pos >> 4, xx = pos & 15;
  const int pbase = (y + 1) * HC + (xx + 1);
  const int c0 = dh * 2;                          // this thread's 2 d-planes

  unsigned qp[8];                                 // 8 x half2 = 16-d Q half
#pragma unroll
  for (int c = 0; c < 2; ++c) {
    uint4 u = qs[(c0 + c) * QP + pos];
    qp[c * 4 + 0] = u.x; qp[c * 4 + 1] = u.y;
    qp[c * 4 + 2] = u.z; qp[c * 4 + 3] = u.w;
  }

  // Batch ALL K reads (18 ds_read_b128) -> one latency exposure.
  uint4 kreg[9][2];
#pragma unroll
  for (int nn = 0; nn < 9; ++nn) {
    const int pn = pbase + (nn / 3 - 1) * HC + (nn % 3 - 1);
    kreg[nn][0] = ks[(c0 + 0) * NPOS + pn];
    kreg[nn][1] = ks[(c0 + 1) * NPOS + pn];
  }

  float att[9];
#pragma unroll
  for (int nn = 0; nn < 9; ++nn) {
    float dot = 0.0f;
#pragma unroll
    for (int c = 0; c < 2; ++c) {                 // 16-d partial (own half)
      dot = dot2(qp[c * 4 + 0], kreg[nn][c].x, dot);
      dot = dot2(qp[c * 4 + 1], kreg[nn][c].y, dot);
      dot = dot2(qp[c * 4 + 2], kreg[nn][c].z, dot);
      dot = dot2(qp[c * 4 + 3], kreg[nn][c].w, dot);
    }
    dot += __shfl_xor(dot, 1);                    // pair lane completes 32-d dot
    att[nn] = dot * 0.17677669529663687f;         // 1/sqrt(32)
  }

  float m = att[0];
#pragma unroll
  for (int nn = 1; nn < 9; ++nn) m = fmaxf(m, att[nn]);
  float ssum = 0.0f;
#pragma unroll
  for (int nn = 0; nn < 9; ++nn) { att[nn] = __expf(att[nn] - m); ssum += att[nn]; }
  const float inv = 1.0f / ssum;

  // Batch ALL V reads (18 ds_read_b128), then PV from regs.
  uint4 vreg[9][2];
#pragma unroll
  for (int nn = 0; nn < 9; ++nn) {
    const int pn = pbase + (nn / 3 - 1) * HC + (nn % 3 - 1);
    vreg[nn][0] = vs[(c0 + 0) * NPOS + pn];
    vreg[nn][1] = vs[(c0 + 1) * NPOS + pn];
  }

  float acc[16];
#pragma unroll
  for (int i = 0; i < 16; ++i) acc[i] = 0.0f;
#pragma unroll
  for (int nn = 0; nn < 9; ++nn) {
    const float wn = att[nn] * inv;
#pragma unroll
    for (int cc = 0; cc < 2; ++cc) {              // d-planes c0+cc
      uint4 vv = vreg[nn][cc];
      f16x2 h0 = *(f16x2*)&vv.x, h1 = *(f16x2*)&vv.y;
      f16x2 h2 = *(f16x2*)&vv.z, h3 = *(f16x2*)&vv.w;
      acc[cc * 8 + 0] = fmaf(wn, (float)h0[0], acc[cc * 8 + 0]);  // v_fma_mix
      acc[cc * 8 + 1] = fmaf(wn, (float)h0[1], acc[cc * 8 + 1]);
      acc[cc * 8 + 2] = fmaf(wn, (float)h1[0], acc[cc * 8 + 2]);
      acc[cc * 8 + 3] = fmaf(wn, (float)h1[1], acc[cc * 8 + 3]);
      acc[cc * 8 + 4] = fmaf(wn, (float)h2[0], acc[cc * 8 + 4]);
      acc[cc * 8 + 5] = fmaf(wn, (float)h2[1], acc[cc * 8 + 5]);
      acc[cc * 8 + 6] = fmaf(wn, (float)h3[0], acc[cc * 8 + 6]);
      acc[cc * 8 + 7] = fmaf(wn, (float)h3[1], acc[cc * 8 + 7]);
    }
  }

  // out [b][C=128][96][96]; channel = g*32 + dh*16 + i; lanes along w
  float* ob = out + ((size_t)b * CIN + (size_t)g * DHEAD + (size_t)dh * 16) * HW
            + (size_t)(h0 + y) * WDIM + (w0 + xx);
#pragma unroll
  for (int i = 0; i < 16; ++i) ob[(size_t)i * HW] = acc[i];
}

extern "C" void kernel_launch(void* const* d_in, const int* in_sizes, int n_in,
                              void* d_out, int out_size, void* d_ws, size_t ws_size,
                              hipStream_t stream) {
  (void)in_sizes; (void)n_in; (void)out_size; (void)ws_size;
  const float* x = (const float*)d_in[0];   // [8,128,96,96]
  const float* W = (const float*)d_in[1];   // [384,128]
  float* out = (float*)d_out;

  uint4* xT = (uint4*)d_ws;                              // 18.87 MB channel-last f16
  uint4* Wf = (uint4*)((char*)d_ws + (size_t)NB * HW * 256);  // 96 KB packed weights

  prep_kernel<<<XBLKS + 24, 256, 0, stream>>>(x, W, xT, Wf);
  fused_kernel<<<dim3(WDIM / TW, HDIM / TH, NB * HEADS), 256, 0, stream>>>(xT, Wf, out);
}